// Round 13
// baseline (184.281 us; speedup 1.0000x reference)
//
#include <hip/hip_runtime.h>
#include <hip/hip_bf16.h>
#include <math.h>

// Qwen3-Next GatedDeltaNet, B=1, S=1024, HIDDEN=2048
// H_K=8, H_V=16, DK=DV=128, KDIM=1024, VDIM=2048, CONV_DIM=4096, KS=4
// Chunked delta rule: C=64, 16 chunks. Single merged prep dispatch
// (NO intra-dispatch producer-consumer edges: ba-GEMV reads W_ba directly).

#define SEQ 1024
#define HID 2048
#define NQKVZ 6144

typedef __attribute__((ext_vector_type(8))) short short8;
typedef __attribute__((ext_vector_type(4))) float f32x4;

__device__ __forceinline__ unsigned short f2bf(float f) {
  __hip_bfloat16 h = __float2bfloat16(f);
  return *reinterpret_cast<unsigned short*>(&h);
}
__device__ __forceinline__ float bf2f(unsigned short u) {
  unsigned int x = ((unsigned int)u) << 16;
  return __int_as_float(x);
}

// async global->LDS, 16B per lane (dest = wave-uniform base + lane*16)
typedef __attribute__((address_space(3))) void lds_void;
typedef const __attribute__((address_space(1))) void g_void;
__device__ __forceinline__ void gload16(const void* g, void* l) {
  __builtin_amdgcn_global_load_lds((g_void*)g, (lds_void*)l, 16, 0, 0);
}

// ---------------------------------------------------------------------------
// prep_kernel: merged {W_qkvz^T, W_out^T, X->bf16, ba-GEMV} roles.
// 1D grid, block-uniform role dispatch:
//   [0,12288)            W_qkvz transpose-cast tiles (192 n x 64 k)
//   [12288,16384)        W_out  transpose-cast tiles (64 x 64)
//   [16384,18432)        cast X -> bf16 (1024 elems/block)
//   [18432,18688)        ba GEMV (4 seq rows/block) — reads W_ba DIRECTLY
// ---------------------------------------------------------------------------
__global__ __launch_bounds__(256) void prep_kernel(
    const float* __restrict__ hid, const float* __restrict__ W_qkvz,
    const float* __restrict__ W_out, const float* __restrict__ W_ba,
    const float* __restrict__ A_log, const float* __restrict__ dt_bias,
    unsigned short* __restrict__ Xb, unsigned short* __restrict__ W1t,
    unsigned short* __restrict__ W2t,
    float* __restrict__ gbuf, float* __restrict__ bet) {
  __shared__ float tile[32][33];
  __shared__ float red[4][32][9];
  int bx = blockIdx.x;
  const int tx = threadIdx.x & 31, ty = threadIdx.x >> 5;

  if (bx < 12288) {  // W_qkvz -> W1t bf16
    const int n0 = (bx % 192) * 32, k0 = (bx / 192) * 32;
#pragma unroll
    for (int r = 0; r < 32; r += 8)
      tile[ty + r][tx] = W_qkvz[(size_t)(k0 + ty + r) * NQKVZ + n0 + tx];
    __syncthreads();
#pragma unroll
    for (int r = 0; r < 32; r += 8)
      W1t[(size_t)(n0 + ty + r) * HID + k0 + tx] = f2bf(tile[tx][ty + r]);
    return;
  }
  bx -= 12288;
  if (bx < 4096) {  // W_out -> W2t bf16
    const int n0 = (bx & 63) * 32, k0 = (bx >> 6) * 32;
#pragma unroll
    for (int r = 0; r < 32; r += 8)
      tile[ty + r][tx] = W_out[(size_t)(k0 + ty + r) * HID + n0 + tx];
    __syncthreads();
#pragma unroll
    for (int r = 0; r < 32; r += 8)
      W2t[(size_t)(n0 + ty + r) * HID + k0 + tx] = f2bf(tile[tx][ty + r]);
    return;
  }
  bx -= 4096;
  if (bx < 2048) {  // X -> bf16
    const int i = (bx * 256 + threadIdx.x) * 4;
    const float4 v = *(const float4*)&hid[i];
    ushort4 o;
    o.x = f2bf(v.x); o.y = f2bf(v.y); o.z = f2bf(v.z); o.w = f2bf(v.w);
    *(ushort4*)&Xb[i] = o;
    return;
  }
  bx -= 2048;
  {  // ba GEMV, 4 seq rows; W_ba[k][32] read directly (coalesced per-k)
    const int col = threadIdx.x & 31;
    const int kg  = threadIdx.x >> 5;
    const int s0  = bx * 4;
    const float* wp = W_ba + (size_t)(kg * 256) * 32 + col;
    const float* xp = hid + (size_t)s0 * HID + kg * 256;

    float a0 = 0.f, a1 = 0.f, a2 = 0.f, a3 = 0.f;
    for (int kk = 0; kk < 256; kk += 4) {
      const float w0 = wp[(kk + 0) * 32];
      const float w1 = wp[(kk + 1) * 32];
      const float w2 = wp[(kk + 2) * 32];
      const float w3 = wp[(kk + 3) * 32];
      const float4 x0 = *(const float4*)&xp[kk];
      const float4 x1 = *(const float4*)&xp[kk + HID];
      const float4 x2 = *(const float4*)&xp[kk + 2 * HID];
      const float4 x3 = *(const float4*)&xp[kk + 3 * HID];
      a0 += x0.x * w0 + x0.y * w1 + x0.z * w2 + x0.w * w3;
      a1 += x1.x * w0 + x1.y * w1 + x1.z * w2 + x1.w * w3;
      a2 += x2.x * w0 + x2.y * w1 + x2.z * w2 + x2.w * w3;
      a3 += x3.x * w0 + x3.y * w1 + x3.z * w2 + x3.w * w3;
    }
    red[0][col][kg] = a0;
    red[1][col][kg] = a1;
    red[2][col][kg] = a2;
    red[3][col][kg] = a3;
    __syncthreads();
    if (threadIdx.x < 128) {
      const int r = threadIdx.x >> 5;
      const int c = threadIdx.x & 31;
      float acc = 0.f;
#pragma unroll
      for (int g = 0; g < 8; ++g) acc += red[r][c][g];
      const int s = s0 + r;
      const int hk = c >> 2, j = c & 3;
      if (j < 2) {
        bet[s * 16 + hk * 2 + j] = 1.f / (1.f + expf(-acc));
      } else {
        const int vh = hk * 2 + (j - 2);
        const float x = acc + dt_bias[vh];
        const float sp = (x > 20.f) ? x : log1pf(expf(x));
        gbuf[s * 16 + vh] = -expf(A_log[vh]) * sp;
      }
    }
  }
}

// ---------------------------------------------------------------------------
// bf16 MFMA GEMM: C[M][N] f32 = A[M][K] @ Bt[N][K]^T, both bf16 K-contiguous.
// Block tile (32*MF)x(32*NF), BK=32*KF, 4 waves (2x2), wave (16MF)x(16NF).
// Double-buffered LDS; global_load_lds width-16 with PRE-SWIZZLED global src.
// ---------------------------------------------------------------------------
#define SWZ(row) ((KF == 1) ? (((row) >> 1) & 3) : ((row) & 7))

template <int MF, int NF, int KF>
__global__ __launch_bounds__(256) void gemm_bf16(const unsigned short* __restrict__ A,
                                                 const unsigned short* __restrict__ Bt,
                                                 float* __restrict__ C,
                                                 int M, int N, int K) {
  constexpr int BM = 32 * MF, BN = 32 * NF, BK = 32 * KF;
  constexpr int RB  = BK * 2;
  constexpr int APW = (BM * KF / 16) / 4;
  constexpr int BPW = (BN * KF / 16) / 4;
  constexpr int RPG = 16 / KF;
  __shared__ unsigned short As[2][BM * BK];
  __shared__ unsigned short Bs[2][BN * BK];

  const int tid  = threadIdx.x;
  const int lane = tid & 63;
  const int w    = tid >> 6;
  const int wm   = w >> 1, wn = w & 1;
  const int row0 = blockIdx.y * BM, col0 = blockIdx.x * BN;

  const int lrow  = (KF == 1) ? (lane >> 2) : (lane >> 3);
  const int lslot = lane & (4 * KF - 1);
  const int arow  = lane & 15;

  f32x4 acc[MF][NF];
#pragma unroll
  for (int m = 0; m < MF; ++m)
#pragma unroll
    for (int n = 0; n < NF; ++n) acc[m][n] = (f32x4){0.f, 0.f, 0.f, 0.f};

  auto stage = [&](int bi, int kt) {
    const int ko = kt * BK;
#pragma unroll
    for (int u = 0; u < APW; ++u) {
      const int gu = w * APW + u;
      const int row = gu * RPG + lrow;
      const int sg = lslot ^ SWZ(row);
      gload16(A + (size_t)(row0 + row) * K + ko + sg * 8,
              (char*)As[bi] + gu * 1024 + lane * 16);
    }
#pragma unroll
    for (int u = 0; u < BPW; ++u) {
      const int gu = w * BPW + u;
      const int row = gu * RPG + lrow;
      const int sg = lslot ^ SWZ(row);
      gload16(Bt + (size_t)(col0 + row) * K + ko + sg * 8,
              (char*)Bs[bi] + gu * 1024 + lane * 16);
    }
  };

  stage(0, 0);
  __syncthreads();

  int cur = 0;
  const int nk = K / BK;
  for (int kt = 0; kt < nk; ++kt) {
    if (kt + 1 < nk) stage(cur ^ 1, kt + 1);

    const char* asb = (const char*)As[cur];
    const char* bsb = (const char*)Bs[cur];
    short8 af[MF][KF], bf[NF][KF];
#pragma unroll
    for (int m = 0; m < MF; ++m)
#pragma unroll
      for (int kk = 0; kk < KF; ++kk) {
        const int row = wm * (16 * MF) + m * 16 + arow;
        const int slot = kk * 4 + (lane >> 4);
        af[m][kk] = *(const short8*)(asb + row * RB + ((slot ^ SWZ(row)) * 16));
      }
#pragma unroll
    for (int n = 0; n < NF; ++n)
#pragma unroll
      for (int kk = 0; kk < KF; ++kk) {
        const int row = wn * (16 * NF) + n * 16 + arow;
        const int slot = kk * 4 + (lane >> 4);
        bf[n][kk] = *(const short8*)(bsb + row * RB + ((slot ^ SWZ(row)) * 16));
      }
#pragma unroll
    for (int m = 0; m < MF; ++m)
#pragma unroll
      for (int n = 0; n < NF; ++n)
#pragma unroll
        for (int kk = 0; kk < KF; ++kk)
          acc[m][n] = __builtin_amdgcn_mfma_f32_16x16x32_bf16(af[m][kk], bf[n][kk],
                                                              acc[m][n], 0, 0, 0);

    __syncthreads();
    cur ^= 1;
  }

#pragma unroll
  for (int m = 0; m < MF; ++m)
#pragma unroll
    for (int n = 0; n < NF; ++n) {
      const int r0 = row0 + wm * (16 * MF) + m * 16 + (lane >> 4) * 4;
      const int c  = col0 + wn * (16 * NF) + n * 16 + (lane & 15);
#pragma unroll
      for (int r = 0; r < 4; ++r)
        C[(size_t)(r0 + r) * N + c] = acc[m][n][r];
    }
}

// ---------------------------------------------------------------------------
// chunk_prep v6: 512 threads (8 waves). Conv input staged via REGISTER
// prefetch pipeline; waves 0-3 KK^T, 4-7 QK^T; wave 0 reg-solve || epilogue.
// ---------------------------------------------------------------------------
#define NT 512
__global__ __launch_bounds__(NT) void chunk_prep(
    const float* __restrict__ qkvz, const float* __restrict__ conv_w,
    const float* __restrict__ gbuf, const float* __restrict__ bet,
    unsigned short* __restrict__ Tg, unsigned short* __restrict__ Gg,
    unsigned short* __restrict__ Wtg, unsigned short* __restrict__ Qtg,
    unsigned short* __restrict__ Khg, float* __restrict__ bvg,
    float* __restrict__ esg) {
  const int h  = blockIdx.x >> 4;
  const int c  = blockIdx.x & 15;
  const int hk = h >> 1;
  const int tid = threadIdx.x;
  const int lane = tid & 63;
  const int w    = tid >> 6;
  const int lr   = lane & 15;
  const int lk   = lane >> 4;

  __shared__ float raw[67][128];
  __shared__ unsigned short Kb[64 * 128];
  __shared__ unsigned short Qb[64 * 128];
  __shared__ unsigned short Bm[64][64];
  __shared__ float cg[64];
  __shared__ float btl[64];

  const int s0 = c * 64;
  const int qcol0 = hk * 768;
  const int kcol0 = hk * 768 + 128;
  const int vcol0 = hk * 768 + 256 + (h & 1) * 128;

  if (tid < 64) {
    float g = gbuf[(s0 + tid) * 16 + h];
#pragma unroll
    for (int d = 1; d < 64; d <<= 1) {
      const float o = __shfl_up(g, d);
      if (tid >= d) g += o;
    }
    cg[tid] = g;
    btl[tid] = bet[(s0 + tid) * 16 + h];
  }

  float4 rq[5], rk[5], rv[5];

#define ISSUE(col0_, rg)                                                      \
  _Pragma("unroll")                                                           \
  for (int ii = 0; ii < 5; ++ii) {                                            \
    const int idx = tid + NT * ii;                                            \
    if (idx < 67 * 32) {                                                      \
      const int r = idx >> 5, cq = (idx & 31) * 4;                            \
      const int sr = s0 - 3 + r;                                              \
      if (sr >= 0)                                                            \
        rg[ii] = *(const float4*)&qkvz[(size_t)sr * NQKVZ + (col0_) + cq];    \
      else { rg[ii].x = 0.f; rg[ii].y = 0.f; rg[ii].z = 0.f; rg[ii].w = 0.f; }\
    }                                                                         \
  }

#define WRITE(rg)                                                             \
  _Pragma("unroll")                                                           \
  for (int ii = 0; ii < 5; ++ii) {                                            \
    const int idx = tid + NT * ii;                                            \
    if (idx < 67 * 32) {                                                      \
      const int r = idx >> 5, cq = (idx & 31) * 4;                            \
      *(float4*)&raw[r][cq] = rg[ii];                                         \
    }                                                                         \
  }

#define CONV_TO(dst, wbase, isq)                                              \
  for (int n = 0; n < 4; ++n) {                                               \
    const int idx = tid + NT * n;                                             \
    const int row = idx >> 5;                                                 \
    const int col = (idx & 31) * 4;                                           \
    float wgt[4][4];                                                          \
    _Pragma("unroll")                                                         \
    for (int x = 0; x < 4; ++x) {                                             \
      const float4 a = *(const float4*)&conv_w[((wbase) + hk * 128 + col + x) * 4]; \
      wgt[x][0] = a.x; wgt[x][1] = a.y; wgt[x][2] = a.z; wgt[x][3] = a.w;     \
    }                                                                         \
    float4 ac = {0.f, 0.f, 0.f, 0.f};                                         \
    _Pragma("unroll")                                                         \
    for (int j = 0; j < 4; ++j) {                                             \
      const float4 xr = *(const float4*)&raw[row + j][col];                   \
      ac.x = fmaf(wgt[0][j], xr.x, ac.x); ac.y = fmaf(wgt[1][j], xr.y, ac.y); \
      ac.z = fmaf(wgt[2][j], xr.z, ac.z); ac.w = fmaf(wgt[3][j], xr.w, ac.w); \
    }                                                                         \
    float4 y;                                                                 \
    y.x = ac.x / (1.f + __expf(-ac.x)); y.y = ac.y / (1.f + __expf(-ac.y));   \
    y.z = ac.z / (1.f + __expf(-ac.z)); y.w = ac.w / (1.f + __expf(-ac.w));   \
    float ss = y.x * y.x + y.y * y.y + y.z * y.z + y.w * y.w;                 \
    _Pragma("unroll")                                                         \
    for (int m = 1; m <= 16; m <<= 1) ss += __shfl_xor(ss, m);                \
    float sc = rsqrtf(ss + 1e-6f);                                            \
    if (isq) sc *= 0.08838834764831845f;                                      \
    const int boff = row * 256 + ((col * 2) ^ ((row & 7) << 4));              \
    ushort4 o = {f2bf(y.x * sc), f2bf(y.y * sc), f2bf(y.z * sc), f2bf(y.w * sc)}; \
    *(ushort4*)((char*)(dst) + boff) = o;                                     \
  }

  ISSUE(qcol0, rq);
  WRITE(rq);
  __syncthreads();
  ISSUE(kcol0, rk);
  CONV_TO(Qb, 0, true);
  __syncthreads();
  WRITE(rk);
  __syncthreads();
  ISSUE(vcol0, rv);
  CONV_TO(Kb, 1024, false);
  __syncthreads();
  WRITE(rv);

  const bool isK = (w < 4);
  const int w4 = w & 3;
  f32x4 dacc[4];
#pragma unroll
  for (int ct = 0; ct < 4; ++ct) dacc[ct] = (f32x4){0.f, 0.f, 0.f, 0.f};
  {
    const int rowA = 16 * w4 + lr;
    const int swA  = (rowA & 7) << 4;
    const char* Ab = isK ? (const char*)Kb : (const char*)Qb;
#pragma unroll
    for (int ks = 0; ks < 4; ++ks) {
      const int kb = ks * 64 + lk * 16;
      const short8 a = *(const short8*)(Ab + rowA * 256 + (kb ^ swA));
#pragma unroll
      for (int ct = 0; ct < 4; ++ct) {
        const int rowB = ct * 16 + lr;
        const short8 bK = *(const short8*)((char*)Kb + rowB * 256 + (kb ^ ((rowB & 7) << 4)));
        dacc[ct] = __builtin_amdgcn_mfma_f32_16x16x32_bf16(a, bK, dacc[ct], 0, 0, 0);
      }
    }
  }
#pragma unroll
  for (int ct = 0; ct < 4; ++ct) {
#pragma unroll
    for (int r = 0; r < 4; ++r) {
      const int i = 16 * w4 + lk * 4 + r;
      const int j = ct * 16 + lr;
      const float e = __expf(cg[i] - cg[j]);
      if (isK) Bm[i][j] = f2bf((j < i) ? btl[i] * e * dacc[ct][r] : 0.f);
      else     Gg[(size_t)blockIdx.x * 4096 + i * 64 + j] =
                   f2bf((j <= i) ? e * dacc[ct][r] : 0.f);
    }
  }
  __syncthreads();

  const float cglast = cg[63];
  if (w == 0) {
    const int l = lane;
    float Tc[64];
#pragma unroll
    for (int i = 0; i < 64; ++i) {
      float v = (i == l) ? 1.f : 0.f;
#pragma unroll
      for (int j = 0; j < i; ++j) v -= bf2f(Bm[i][j]) * Tc[j];
      Tc[i] = v;
    }
#pragma unroll
    for (int i = 0; i < 64; ++i)
      Tg[(size_t)blockIdx.x * 4096 + i * 64 + l] = f2bf(Tc[i]);
    if (lane == 0) esg[blockIdx.x] = __expf(cglast);
  } else {
    const int t2 = tid - 64;
    for (int idx = t2; idx < 2048; idx += 448) {
      const int i = idx >> 5;
      const int dk = (idx & 31) * 4;
      const int boff = i * 256 + ((dk * 2) ^ ((i & 7) << 4));
      const ushort4 kq = *(const ushort4*)((char*)Kb + boff);
      const ushort4 qq = *(const ushort4*)((char*)Qb + boff);
      const float ei = __expf(cg[i]);
      const float wi = btl[i] * ei;
      ushort4 wo = {f2bf(wi * bf2f(kq.x)), f2bf(wi * bf2f(kq.y)),
                    f2bf(wi * bf2f(kq.z)), f2bf(wi * bf2f(kq.w))};
      ushort4 qo = {f2bf(ei * bf2f(qq.x)), f2bf(ei * bf2f(qq.y)),
                    f2bf(ei * bf2f(qq.z)), f2bf(ei * bf2f(qq.w))};
      *(ushort4*)&Wtg[(size_t)blockIdx.x * 8192 + i * 128 + dk] = wo;
      *(ushort4*)&Qtg[(size_t)blockIdx.x * 8192 + i * 128 + dk] = qo;

      float wv[4][4];
#pragma unroll
      for (int x = 0; x < 4; ++x) {
        const float4 a = *(const float4*)&conv_w[(2048 + h * 128 + dk + x) * 4];
        wv[x][0] = a.x; wv[x][1] = a.y; wv[x][2] = a.z; wv[x][3] = a.w;
      }
      float4 va = {0.f, 0.f, 0.f, 0.f};
#pragma unroll
      for (int j = 0; j < 4; ++j) {
        const float4 xv = *(const float4*)&raw[i + j][dk];
        va.x = fmaf(wv[0][j], xv.x, va.x); va.y = fmaf(wv[1][j], xv.y, va.y);
        va.z = fmaf(wv[2][j], xv.z, va.z); va.w = fmaf(wv[3][j], xv.w, va.w);
      }
      float4 bv4;
      bv4.x = btl[i] * va.x / (1.f + __expf(-va.x));
      bv4.y = btl[i] * va.y / (1.f + __expf(-va.y));
      bv4.z = btl[i] * va.z / (1.f + __expf(-va.z));
      bv4.w = btl[i] * va.w / (1.f + __expf(-va.w));
      *(float4*)&bvg[(size_t)blockIdx.x * 8192 + i * 128 + dk] = bv4;
    }
    for (int lin = t2; lin < 8192; lin += 448) {
      const int dk = lin >> 6, i = lin & 63;
      const unsigned short kraw =
          *(const unsigned short*)((char*)Kb + i * 256 + ((dk * 2) ^ ((i & 7) << 4)));
      Khg[(size_t)blockIdx.x * 8192 + lin] = f2bf(__expf(cglast - cg[i]) * bf2f(kraw));
    }
  }
#undef ISSUE
#undef WRITE
#undef CONV_TO
}
#undef NT

// ---------------------------------------------------------------------------
// scan_rec: serial over 16 chunks, (h, dv-block) parallel,
// h = bid&15 -> same-head blocks share one XCD's L2; reg-prefetch 2 sets.
// ---------------------------------------------------------------------------
struct SFrags {
  short8 wf[4];
  short8 tf[2];
  short8 qf[4];
  short8 gf[2];
  short8 kh[2][2];
  float  bv[4];
  float  es;
};

__device__ __forceinline__ void sload(SFrags& F,
    const unsigned short* __restrict__ Tg, const unsigned short* __restrict__ Gg,
    const unsigned short* __restrict__ Wtg, const unsigned short* __restrict__ Qtg,
    const unsigned short* __restrict__ Khg, const float* __restrict__ bvg,
    const float* __restrict__ esg,
    size_t base, int w, int lr, int lk, int dv0) {
  const unsigned short* T_  = Tg  + base * 4096;
  const unsigned short* G_  = Gg  + base * 4096;
  const unsigned short* W_  = Wtg + base * 8192;
  const unsigned short* Q_  = Qtg + base * 8192;
  const unsigned short* Kh_ = Khg + base * 8192;
  const float* bv_ = bvg + base * 8192;
#pragma unroll
  for (int ks = 0; ks < 4; ++ks) {
    F.wf[ks] = *(const short8*)(W_ + (16 * w + lr) * 128 + ks * 32 + lk * 8);
    F.qf[ks] = *(const short8*)(Q_ + (16 * w + lr) * 128 + ks * 32 + lk * 8);
  }
#pragma unroll
  for (int ks = 0; ks < 2; ++ks) {
    F.tf[ks]    = *(const short8*)(T_ + (16 * w + lr) * 64 + ks * 32 + lk * 8);
    F.gf[ks]    = *(const short8*)(G_ + (16 * w + lr) * 64 + ks * 32 + lk * 8);
    F.kh[0][ks] = *(const short8*)(Kh_ + (32 * w + lr) * 64 + ks * 32 + lk * 8);
    F.kh[1][ks] = *(const short8*)(Kh_ + (32 * w + 16 + lr) * 64 + ks * 32 + lk * 8);
  }
#pragma unroll
  for (int r = 0; r < 4; ++r)
    F.bv[r] = bv_[(16 * w + lk * 4 + r) * 128 + dv0 + lr];
  F.es = esg[base];
}

__global__ __launch_bounds__(256) void scan_rec(
    const unsigned short* __restrict__ Tg, const unsigned short* __restrict__ Gg,
    const unsigned short* __restrict__ Wtg, const unsigned short* __restrict__ Qtg,
    const unsigned short* __restrict__ Khg, const float* __restrict__ bvg,
    const float* __restrict__ esg, float* __restrict__ obuf) {
  const int h   = blockIdx.x & 15;
  const int dvb = blockIdx.x >> 4;
  const int dv0 = dvb * 16;
  const int tid = threadIdx.x;
  const int lane = tid & 63;
  const int w   = tid >> 6;
  const int lr  = lane & 15;
  const int lk  = lane >> 4;

  __shared__ unsigned short Sb[16][136];
  __shared__ unsigned short Ub[16][72];
  __shared__ unsigned short Db[16][72];

  for (int n = tid; n < 16 * 136 / 2; n += 256) ((unsigned int*)Sb)[n] = 0u;

  f32x4 sacc0 = {0.f, 0.f, 0.f, 0.f};
  f32x4 sacc1 = {0.f, 0.f, 0.f, 0.f};

  SFrags fA, fB;
  sload(fA, Tg, Gg, Wtg, Qtg, Khg, bvg, esg, (size_t)h * 16, w, lr, lk, dv0);
  __syncthreads();

#define SCAN_CHUNK(F, c)                                                      \
  {                                                                           \
    short8 sb[4];                                                             \
    _Pragma("unroll")                                                         \
    for (int ks = 0; ks < 4; ++ks)                                            \
      sb[ks] = *(const short8*)(&Sb[lr][ks * 32 + lk * 8]);                   \
    f32x4 au = {0.f, 0.f, 0.f, 0.f};                                          \
    _Pragma("unroll")                                                         \
    for (int ks = 0; ks < 4; ++ks)                                            \
      au = __builtin_amdgcn_mfma_f32_16x16x32_bf16(F.wf[ks], sb[ks], au, 0, 0, 0); \
    {                                                                         \
      ushort4 pk;                                                             \
      _Pragma("unroll")                                                       \
      for (int r = 0; r < 4; ++r)                                             \
        ((unsigned short*)&pk)[r] = f2bf(F.bv[r] - au[r]);                    \
      *(ushort4*)&Ub[lr][16 * w + lk * 4] = pk;                               \
    }                                                                         \
    __syncthreads();                                                          \
    f32x4 ad = {0.f, 0.f, 0.f, 0.f};                                          \
    _Pragma("unroll")                                                         \
    for (int ks = 0; ks < 2; ++ks) {                                          \
      const short8 ub = *(const short8*)(&Ub[lr][ks * 32 + lk * 8]);          \
      ad = __builtin_amdgcn_mfma_f32_16x16x32_bf16(F.tf[ks], ub, ad, 0, 0, 0); \
    }                                                                         \
    {                                                                         \
      ushort4 pk;                                                             \
      _Pragma("unroll")                                                       \
      for (int r = 0; r < 4; ++r) ((unsigned short*)&pk)[r] = f2bf(ad[r]);    \
      *(ushort4*)&Db[lr][16 * w + lk * 4] = pk;                               \
    }                                                                         \
    __syncthreads();                                                          \
    short8 dbf[2];                                                            \
    _Pragma("unroll")                                                         \
    for (int ks = 0; ks < 2; ++ks)                                            \
      dbf[ks] = *(const short8*)(&Db[lr][ks * 32 + lk * 8]);                  \
    f32x4 ao = {0.f, 0.f, 0.f, 0.f};                                          \
    _Pragma("unroll")                                                         \
    for (int ks = 0; ks < 4; ++ks)                                            \
      ao = __builtin_amdgcn_mfma_f32_16x16x32_bf16(F.qf[ks], sb[ks], ao, 0, 0, 0); \
    _Pragma("unroll")                                                         \
    for (int ks = 0; ks < 2; ++ks)                                            \
      ao = __builtin_amdgcn_mfma_f32_16x16x32_bf16(F.gf[ks], dbf[ks], ao, 0, 0, 0); \
    _Pragma("unroll")                                                         \
    for (int r = 0; r < 4; ++r) {                                             \
      const int i = 16 * w + lk * 4 + r;                                      \
      obuf[((size_t)((c) * 64 + i) * 16 + h) * 128 + dv0 + lr] = ao[r];       \
    }                                                                         \
    sacc0 *= F.es;                                                            \
    sacc1 *= F.es;                                                            \
    _Pragma("unroll")                                                         \
    for (int ks = 0; ks < 2; ++ks) {                                          \
      sacc0 = __builtin_amdgcn_mfma_f32_16x16x32_bf16(F.kh[0][ks], dbf[ks], sacc0, 0, 0, 0); \
      sacc1 = __builtin_amdgcn_mfma_f32_16x16x32_bf16(F.kh[1][ks], dbf[ks], sacc1, 0, 0, 0); \
    }                                                                         \
    {                                                                         \
      ushort4 p0, p1;                                                         \
      _Pragma("unroll")                                                       \
      for (int r = 0; r < 4; ++r) {                                           \
        ((unsigned short*)&p0)[r] = f2bf(sacc0[r]);                           \
        ((unsigned short*)&p1)[r] = f2bf(sacc1[r]);                           \
      }                                                                       \
      *(ushort4*)&Sb[lr][32 * w + lk * 4] = p0;                               \
      *(ushort4*)&Sb[lr][32 * w + 16 + lk * 4] = p1;                          \
    }                                                                         \
    __syncthreads();                                                          \
  }

  for (int c = 0; c < 16; c += 2) {
    const int c1 = (c + 1 < 15) ? c + 1 : 15;
    const int c2 = (c + 2 < 15) ? c + 2 : 15;
    sload(fB, Tg, Gg, Wtg, Qtg, Khg, bvg, esg, (size_t)h * 16 + c1, w, lr, lk, dv0);
    SCAN_CHUNK(fA, c);
    sload(fA, Tg, Gg, Wtg, Qtg, Khg, bvg, esg, (size_t)h * 16 + c2, w, lr, lk, dv0);
    SCAN_CHUNK(fB, c + 1);
  }
#undef SCAN_CHUNK
}

// ---------------------------------------------------------------------------
// gated RMSNorm -> bf16. 1024 blocks x 256 thr; block = one s, two vh at a
// time (threads 0-127 / 128-255), 8 iterations.
// ---------------------------------------------------------------------------
__global__ __launch_bounds__(256) void rmsnorm_kernel(const float* __restrict__ obuf,
                                                      const float* __restrict__ qkvz,
                                                      const float* __restrict__ nw,
                                                      unsigned short* __restrict__ on) {
  const int s    = blockIdx.x;
  const int half = threadIdx.x >> 7;
  const int d    = threadIdx.x & 127;
  __shared__ float red[4];

  for (int it = 0; it < 8; ++it) {
    const int vh = it * 2 + half;
    const float x = obuf[((size_t)s * 16 + vh) * 128 + d];
    float ss = x * x;
#pragma unroll
    for (int m = 1; m < 64; m <<= 1) ss += __shfl_xor(ss, m);
    if ((threadIdx.x & 63) == 0) red[threadIdx.x >> 6] = ss;
    __syncthreads();
    const float tot = red[half * 2] + red[half * 2 + 1];

    const float z = qkvz[(size_t)s * NQKVZ + (vh >> 1) * 768 + 512 + (vh & 1) * 128 + d];
    const float y = x * rsqrtf(tot * (1.f / 128.f) + 1e-6f) * nw[d] *
                    (z / (1.f + expf(-z)));
    on[(size_t)s * 2048 + vh * 128 + d] = f2bf(y);
    __syncthreads();
  }
}

// ---------------------------------------------------------------------------
extern "C" void kernel_launch(void* const* d_in, const int* in_sizes, int n_in,
                              void* d_out, int out_size, void* d_ws, size_t ws_size,
                              hipStream_t stream) {
  const float* hid     = (const float*)d_in[0];
  const float* W_qkvz  = (const float*)d_in[1];
  const float* W_ba    = (const float*)d_in[2];
  const float* conv_w  = (const float*)d_in[3];
  const float* dt_bias = (const float*)d_in[4];
  const float* A_log   = (const float*)d_in[5];
  const float* norm_w  = (const float*)d_in[6];
  const float* W_out   = (const float*)d_in[7];
  float* out = (float*)d_out;

  char* ws = (char*)d_ws;
  float* qkvz = (float*)ws;                 ws += (size_t)SEQ * NQKVZ * 4;   // 24 MB
  char* region2 = ws;                       ws += (size_t)HID * NQKVZ * 2;   // 24 MB
  unsigned short* W1t = (unsigned short*)region2;
  float* obuf = (float*)(region2 + 16777216);
  unsigned short* Xb = (unsigned short*)ws; ws += (size_t)SEQ * HID * 2;     // 4 MB
  unsigned short* on_bf = Xb;
  unsigned short* W2t = (unsigned short*)ws; ws += (size_t)HID * HID * 2;    // 8 MB
  float* gbuf = (float*)ws;                  ws += (size_t)SEQ * 16 * 4;
  float* bet  = (float*)ws;                  ws += (size_t)SEQ * 16 * 4;
  unsigned short* Tg  = (unsigned short*)ws; ws += (size_t)256 * 4096 * 2;
  unsigned short* Gg  = (unsigned short*)ws; ws += (size_t)256 * 4096 * 2;
  unsigned short* Wtg = (unsigned short*)ws; ws += (size_t)256 * 8192 * 2;
  unsigned short* Qtg = (unsigned short*)ws; ws += (size_t)256 * 8192 * 2;
  unsigned short* Khg = (unsigned short*)ws; ws += (size_t)256 * 8192 * 2;
  float* bvg          = (float*)ws;          ws += (size_t)256 * 8192 * 4;
  float* esg          = (float*)ws;          ws += 256 * 4;

  // merged prep: W1t, W2t, Xb, gbuf/bet in ONE dispatch (no intra-deps)
  prep_kernel<<<dim3(18688), 256, 0, stream>>>(hid, W_qkvz, W_out, W_ba,
                                               A_log, dt_bias,
                                               Xb, W1t, W2t, gbuf, bet);
  // qkvz = X @ W_qkvz  (64x128 tile, BK=64 -> 768 blocks = 3/CU)
  gemm_bf16<2, 4, 2><<<dim3(NQKVZ / 128, SEQ / 64), 256, 0, stream>>>(Xb, W1t, qkvz,
                                                                      SEQ, NQKVZ, HID);
  chunk_prep<<<dim3(256), 512, 0, stream>>>(qkvz, conv_w, gbuf, bet,
                                            Tg, Gg, Wtg, Qtg, Khg, bvg, esg);
  scan_rec<<<dim3(128), 256, 0, stream>>>(Tg, Gg, Wtg, Qtg, Khg, bvg, esg, obuf);
  rmsnorm_kernel<<<dim3(SEQ), 256, 0, stream>>>(obuf, qkvz, norm_w, on_bf);
  // out = on @ W_out  (64x64 tile, BK=64 -> 512 blocks = 2/CU)
  gemm_bf16<2, 2, 2><<<dim3(HID / 64, SEQ / 64), 256, 0, stream>>>(on_bf, W2t, out,
                                                                   SEQ, HID, HID);
}

// Round 14
// 173.544 us; speedup vs baseline: 1.0619x; 1.0619x over previous
//
#include <hip/hip_runtime.h>
#include <hip/hip_bf16.h>
#include <math.h>

// Qwen3-Next GatedDeltaNet, B=1, S=1024, HIDDEN=2048
// H_K=8, H_V=16, DK=DV=128, KDIM=1024, VDIM=2048, CONV_DIM=4096, KS=4
// Chunked delta rule: C=64, 16 chunks.

#define SEQ 1024
#define HID 2048
#define NQKVZ 6144

typedef __attribute__((ext_vector_type(8))) short short8;
typedef __attribute__((ext_vector_type(4))) float f32x4;

__device__ __forceinline__ unsigned short f2bf(float f) {
  __hip_bfloat16 h = __float2bfloat16(f);
  return *reinterpret_cast<unsigned short*>(&h);
}
__device__ __forceinline__ float bf2f(unsigned short u) {
  unsigned int x = ((unsigned int)u) << 16;
  return __int_as_float(x);
}

// async global->LDS, 16B per lane (dest = wave-uniform base + lane*16)
typedef __attribute__((address_space(3))) void lds_void;
typedef const __attribute__((address_space(1))) void g_void;
__device__ __forceinline__ void gload16(const void* g, void* l) {
  __builtin_amdgcn_global_load_lds((g_void*)g, (lds_void*)l, 16, 0, 0);
}

// ---------------------------------------------------------------------------
// elementwise f32 -> bf16 cast
// ---------------------------------------------------------------------------
__global__ __launch_bounds__(256) void cast_bf16(const float* __restrict__ in,
                                                 unsigned short* __restrict__ out,
                                                 int n) {
  const int i = (blockIdx.x * 256 + threadIdx.x) * 4;
  if (i < n) {
    const float4 v = *(const float4*)&in[i];
    ushort4 o;
    o.x = f2bf(v.x); o.y = f2bf(v.y); o.z = f2bf(v.z); o.w = f2bf(v.w);
    *(ushort4*)&out[i] = o;
  }
}

// ---------------------------------------------------------------------------
// merged W_qkvz / W_out transpose-cast v2: 64x64 tiles, float4 I/O.
// grid (128, 32): bx<96 -> W_qkvz (96 n-tiles), else W_out (32 n-tiles).
// Reads 256B/row-wavefront, writes 128B/row; LDS column reads 2-way (free).
// ---------------------------------------------------------------------------
__global__ __launch_bounds__(256) void transpose_cast2(const float* __restrict__ W1,
                                                       unsigned short* __restrict__ W1t,
                                                       const float* __restrict__ W2,
                                                       unsigned short* __restrict__ W2t) {
  __shared__ float tile[64][65];
  int bx = blockIdx.x;
  const float* W;
  unsigned short* Wt;
  int N;
  if (bx < 96) { W = W1; Wt = W1t; N = NQKVZ; }
  else         { W = W2; Wt = W2t; N = HID; bx -= 96; }
  const int n0 = bx * 64, k0 = blockIdx.y * 64;
  const int tc = (threadIdx.x & 15) * 4;   // col group (x4)
  const int tr = threadIdx.x >> 4;         // 0..15

#pragma unroll
  for (int rr = 0; rr < 64; rr += 16) {
    const float4 v = *(const float4*)&W[(size_t)(k0 + tr + rr) * N + n0 + tc];
    *(float4*)&tile[tr + rr][tc] = v;
  }
  __syncthreads();
#pragma unroll
  for (int rr = 0; rr < 64; rr += 16) {
    const int r = tr + rr;
    ushort4 o;
    o.x = f2bf(tile[tc + 0][r]);
    o.y = f2bf(tile[tc + 1][r]);
    o.z = f2bf(tile[tc + 2][r]);
    o.w = f2bf(tile[tc + 3][r]);
    *(ushort4*)&Wt[(size_t)(n0 + r) * HID + k0 + tc] = o;
  }
}

// ---------------------------------------------------------------------------
// W_ba[2048][32] f32 -> Wbt[32][2048] f32
// ---------------------------------------------------------------------------
__global__ __launch_bounds__(256) void transpose_f32(const float* __restrict__ W,
                                                     float* __restrict__ Wt) {
  __shared__ float tile[32][33];
  const int k0 = blockIdx.x * 32;
  const int tx = threadIdx.x & 31, ty = threadIdx.x >> 5;
#pragma unroll
  for (int r = 0; r < 32; r += 8)
    tile[ty + r][tx] = W[(size_t)(k0 + ty + r) * 32 + tx];
  __syncthreads();
#pragma unroll
  for (int r = 0; r < 32; r += 8)
    Wt[(size_t)(ty + r) * HID + k0 + tx] = tile[tx][ty + r];
}

// ---------------------------------------------------------------------------
// ba: split-K GEMV vs Wbt[32][2048] f32, fused activations.
// ---------------------------------------------------------------------------
__global__ __launch_bounds__(256) void ba_kernel(const float* __restrict__ X,
                                                 const float* __restrict__ Wbt,
                                                 const float* __restrict__ A_log,
                                                 const float* __restrict__ dt_bias,
                                                 float* __restrict__ gbuf,
                                                 float* __restrict__ bet) {
  const int col = threadIdx.x & 31;
  const int kg  = threadIdx.x >> 5;
  const int s0  = blockIdx.x * 4;
  const float* wp = Wbt + (size_t)col * HID + kg * 256;
  const float* xp = X + (size_t)s0 * HID + kg * 256;

  float a0 = 0.f, a1 = 0.f, a2 = 0.f, a3 = 0.f;
  for (int kk = 0; kk < 256; kk += 4) {
    const float4 w4 = *(const float4*)&wp[kk];
    const float4 x0 = *(const float4*)&xp[kk];
    const float4 x1 = *(const float4*)&xp[kk + HID];
    const float4 x2 = *(const float4*)&xp[kk + 2 * HID];
    const float4 x3 = *(const float4*)&xp[kk + 3 * HID];
    a0 += x0.x * w4.x + x0.y * w4.y + x0.z * w4.z + x0.w * w4.w;
    a1 += x1.x * w4.x + x1.y * w4.y + x1.z * w4.z + x1.w * w4.w;
    a2 += x2.x * w4.x + x2.y * w4.y + x2.z * w4.z + x2.w * w4.w;
    a3 += x3.x * w4.x + x3.y * w4.y + x3.z * w4.z + x3.w * w4.w;
  }
  __shared__ float red[4][32][9];
  red[0][col][kg] = a0;
  red[1][col][kg] = a1;
  red[2][col][kg] = a2;
  red[3][col][kg] = a3;
  __syncthreads();
  if (threadIdx.x < 128) {
    const int r = threadIdx.x >> 5;
    const int c = threadIdx.x & 31;
    float acc = 0.f;
#pragma unroll
    for (int g = 0; g < 8; ++g) acc += red[r][c][g];
    const int s = s0 + r;
    const int hk = c >> 2, j = c & 3;
    if (j < 2) {
      bet[s * 16 + hk * 2 + j] = 1.f / (1.f + expf(-acc));
    } else {
      const int vh = hk * 2 + (j - 2);
      const float x = acc + dt_bias[vh];
      const float sp = (x > 20.f) ? x : log1pf(expf(x));
      gbuf[s * 16 + vh] = -expf(A_log[vh]) * sp;
    }
  }
}

// ---------------------------------------------------------------------------
// bf16 MFMA GEMM: C[M][N] f32 = A[M][K] @ Bt[N][K]^T, both bf16 K-contiguous.
// Block tile (32*MF)x(32*NF), BK=32*KF, 4 waves (2x2), wave (16MF)x(16NF).
// Double-buffered LDS; global_load_lds width-16 with PRE-SWIZZLED global src.
// ---------------------------------------------------------------------------
#define SWZ(row) ((KF == 1) ? (((row) >> 1) & 3) : ((row) & 7))

template <int MF, int NF, int KF>
__global__ __launch_bounds__(256) void gemm_bf16(const unsigned short* __restrict__ A,
                                                 const unsigned short* __restrict__ Bt,
                                                 float* __restrict__ C,
                                                 int M, int N, int K) {
  constexpr int BM = 32 * MF, BN = 32 * NF, BK = 32 * KF;
  constexpr int RB  = BK * 2;
  constexpr int APW = (BM * KF / 16) / 4;
  constexpr int BPW = (BN * KF / 16) / 4;
  constexpr int RPG = 16 / KF;
  __shared__ unsigned short As[2][BM * BK];
  __shared__ unsigned short Bs[2][BN * BK];

  const int tid  = threadIdx.x;
  const int lane = tid & 63;
  const int w    = tid >> 6;
  const int wm   = w >> 1, wn = w & 1;
  const int row0 = blockIdx.y * BM, col0 = blockIdx.x * BN;

  const int lrow  = (KF == 1) ? (lane >> 2) : (lane >> 3);
  const int lslot = lane & (4 * KF - 1);
  const int arow  = lane & 15;

  f32x4 acc[MF][NF];
#pragma unroll
  for (int m = 0; m < MF; ++m)
#pragma unroll
    for (int n = 0; n < NF; ++n) acc[m][n] = (f32x4){0.f, 0.f, 0.f, 0.f};

  auto stage = [&](int bi, int kt) {
    const int ko = kt * BK;
#pragma unroll
    for (int u = 0; u < APW; ++u) {
      const int gu = w * APW + u;
      const int row = gu * RPG + lrow;
      const int sg = lslot ^ SWZ(row);
      gload16(A + (size_t)(row0 + row) * K + ko + sg * 8,
              (char*)As[bi] + gu * 1024 + lane * 16);
    }
#pragma unroll
    for (int u = 0; u < BPW; ++u) {
      const int gu = w * BPW + u;
      const int row = gu * RPG + lrow;
      const int sg = lslot ^ SWZ(row);
      gload16(Bt + (size_t)(col0 + row) * K + ko + sg * 8,
              (char*)Bs[bi] + gu * 1024 + lane * 16);
    }
  };

  stage(0, 0);
  __syncthreads();

  int cur = 0;
  const int nk = K / BK;
  for (int kt = 0; kt < nk; ++kt) {
    if (kt + 1 < nk) stage(cur ^ 1, kt + 1);

    const char* asb = (const char*)As[cur];
    const char* bsb = (const char*)Bs[cur];
    short8 af[MF][KF], bf[NF][KF];
#pragma unroll
    for (int m = 0; m < MF; ++m)
#pragma unroll
      for (int kk = 0; kk < KF; ++kk) {
        const int row = wm * (16 * MF) + m * 16 + arow;
        const int slot = kk * 4 + (lane >> 4);
        af[m][kk] = *(const short8*)(asb + row * RB + ((slot ^ SWZ(row)) * 16));
      }
#pragma unroll
    for (int n = 0; n < NF; ++n)
#pragma unroll
      for (int kk = 0; kk < KF; ++kk) {
        const int row = wn * (16 * NF) + n * 16 + arow;
        const int slot = kk * 4 + (lane >> 4);
        bf[n][kk] = *(const short8*)(bsb + row * RB + ((slot ^ SWZ(row)) * 16));
      }
#pragma unroll
    for (int m = 0; m < MF; ++m)
#pragma unroll
      for (int n = 0; n < NF; ++n)
#pragma unroll
        for (int kk = 0; kk < KF; ++kk)
          acc[m][n] = __builtin_amdgcn_mfma_f32_16x16x32_bf16(af[m][kk], bf[n][kk],
                                                              acc[m][n], 0, 0, 0);

    __syncthreads();
    cur ^= 1;
  }

#pragma unroll
  for (int m = 0; m < MF; ++m)
#pragma unroll
    for (int n = 0; n < NF; ++n) {
      const int r0 = row0 + wm * (16 * MF) + m * 16 + (lane >> 4) * 4;
      const int c  = col0 + wn * (16 * NF) + n * 16 + (lane & 15);
#pragma unroll
      for (int r = 0; r < 4; ++r)
        C[(size_t)(r0 + r) * N + c] = acc[m][n][r];
    }
}

// ---------------------------------------------------------------------------
// chunk_prep v6: 512 threads (8 waves). Conv input staged via REGISTER
// prefetch pipeline; waves 0-3 KK^T, 4-7 QK^T; wave 0 reg-solve || epilogue.
// ---------------------------------------------------------------------------
#define NT 512
__global__ __launch_bounds__(NT) void chunk_prep(
    const float* __restrict__ qkvz, const float* __restrict__ conv_w,
    const float* __restrict__ gbuf, const float* __restrict__ bet,
    unsigned short* __restrict__ Tg, unsigned short* __restrict__ Gg,
    unsigned short* __restrict__ Wtg, unsigned short* __restrict__ Qtg,
    unsigned short* __restrict__ Khg, float* __restrict__ bvg,
    float* __restrict__ esg) {
  const int h  = blockIdx.x >> 4;
  const int c  = blockIdx.x & 15;
  const int hk = h >> 1;
  const int tid = threadIdx.x;
  const int lane = tid & 63;
  const int w    = tid >> 6;
  const int lr   = lane & 15;
  const int lk   = lane >> 4;

  __shared__ float raw[67][128];
  __shared__ unsigned short Kb[64 * 128];
  __shared__ unsigned short Qb[64 * 128];
  __shared__ unsigned short Bm[64][64];
  __shared__ float cg[64];
  __shared__ float btl[64];

  const int s0 = c * 64;
  const int qcol0 = hk * 768;
  const int kcol0 = hk * 768 + 128;
  const int vcol0 = hk * 768 + 256 + (h & 1) * 128;

  if (tid < 64) {
    float g = gbuf[(s0 + tid) * 16 + h];
#pragma unroll
    for (int d = 1; d < 64; d <<= 1) {
      const float o = __shfl_up(g, d);
      if (tid >= d) g += o;
    }
    cg[tid] = g;
    btl[tid] = bet[(s0 + tid) * 16 + h];
  }

  float4 rq[5], rk[5], rv[5];

#define ISSUE(col0_, rg)                                                      \
  _Pragma("unroll")                                                           \
  for (int ii = 0; ii < 5; ++ii) {                                            \
    const int idx = tid + NT * ii;                                            \
    if (idx < 67 * 32) {                                                      \
      const int r = idx >> 5, cq = (idx & 31) * 4;                            \
      const int sr = s0 - 3 + r;                                              \
      if (sr >= 0)                                                            \
        rg[ii] = *(const float4*)&qkvz[(size_t)sr * NQKVZ + (col0_) + cq];    \
      else { rg[ii].x = 0.f; rg[ii].y = 0.f; rg[ii].z = 0.f; rg[ii].w = 0.f; }\
    }                                                                         \
  }

#define WRITE(rg)                                                             \
  _Pragma("unroll")                                                           \
  for (int ii = 0; ii < 5; ++ii) {                                            \
    const int idx = tid + NT * ii;                                            \
    if (idx < 67 * 32) {                                                      \
      const int r = idx >> 5, cq = (idx & 31) * 4;                            \
      *(float4*)&raw[r][cq] = rg[ii];                                         \
    }                                                                         \
  }

#define CONV_TO(dst, wbase, isq)                                              \
  for (int n = 0; n < 4; ++n) {                                               \
    const int idx = tid + NT * n;                                             \
    const int row = idx >> 5;                                                 \
    const int col = (idx & 31) * 4;                                           \
    float wgt[4][4];                                                          \
    _Pragma("unroll")                                                         \
    for (int x = 0; x < 4; ++x) {                                             \
      const float4 a = *(const float4*)&conv_w[((wbase) + hk * 128 + col + x) * 4]; \
      wgt[x][0] = a.x; wgt[x][1] = a.y; wgt[x][2] = a.z; wgt[x][3] = a.w;     \
    }                                                                         \
    float4 ac = {0.f, 0.f, 0.f, 0.f};                                         \
    _Pragma("unroll")                                                         \
    for (int j = 0; j < 4; ++j) {                                             \
      const float4 xr = *(const float4*)&raw[row + j][col];                   \
      ac.x = fmaf(wgt[0][j], xr.x, ac.x); ac.y = fmaf(wgt[1][j], xr.y, ac.y); \
      ac.z = fmaf(wgt[2][j], xr.z, ac.z); ac.w = fmaf(wgt[3][j], xr.w, ac.w); \
    }                                                                         \
    float4 y;                                                                 \
    y.x = ac.x / (1.f + __expf(-ac.x)); y.y = ac.y / (1.f + __expf(-ac.y));   \
    y.z = ac.z / (1.f + __expf(-ac.z)); y.w = ac.w / (1.f + __expf(-ac.w));   \
    float ss = y.x * y.x + y.y * y.y + y.z * y.z + y.w * y.w;                 \
    _Pragma("unroll")                                                         \
    for (int m = 1; m <= 16; m <<= 1) ss += __shfl_xor(ss, m);                \
    float sc = rsqrtf(ss + 1e-6f);                                            \
    if (isq) sc *= 0.08838834764831845f;                                      \
    const int boff = row * 256 + ((col * 2) ^ ((row & 7) << 4));              \
    ushort4 o = {f2bf(y.x * sc), f2bf(y.y * sc), f2bf(y.z * sc), f2bf(y.w * sc)}; \
    *(ushort4*)((char*)(dst) + boff) = o;                                     \
  }

  ISSUE(qcol0, rq);
  WRITE(rq);
  __syncthreads();
  ISSUE(kcol0, rk);
  CONV_TO(Qb, 0, true);
  __syncthreads();
  WRITE(rk);
  __syncthreads();
  ISSUE(vcol0, rv);
  CONV_TO(Kb, 1024, false);
  __syncthreads();
  WRITE(rv);

  const bool isK = (w < 4);
  const int w4 = w & 3;
  f32x4 dacc[4];
#pragma unroll
  for (int ct = 0; ct < 4; ++ct) dacc[ct] = (f32x4){0.f, 0.f, 0.f, 0.f};
  {
    const int rowA = 16 * w4 + lr;
    const int swA  = (rowA & 7) << 4;
    const char* Ab = isK ? (const char*)Kb : (const char*)Qb;
#pragma unroll
    for (int ks = 0; ks < 4; ++ks) {
      const int kb = ks * 64 + lk * 16;
      const short8 a = *(const short8*)(Ab + rowA * 256 + (kb ^ swA));
#pragma unroll
      for (int ct = 0; ct < 4; ++ct) {
        const int rowB = ct * 16 + lr;
        const short8 bK = *(const short8*)((char*)Kb + rowB * 256 + (kb ^ ((rowB & 7) << 4)));
        dacc[ct] = __builtin_amdgcn_mfma_f32_16x16x32_bf16(a, bK, dacc[ct], 0, 0, 0);
      }
    }
  }
#pragma unroll
  for (int ct = 0; ct < 4; ++ct) {
#pragma unroll
    for (int r = 0; r < 4; ++r) {
      const int i = 16 * w4 + lk * 4 + r;
      const int j = ct * 16 + lr;
      const float e = __expf(cg[i] - cg[j]);
      if (isK) Bm[i][j] = f2bf((j < i) ? btl[i] * e * dacc[ct][r] : 0.f);
      else     Gg[(size_t)blockIdx.x * 4096 + i * 64 + j] =
                   f2bf((j <= i) ? e * dacc[ct][r] : 0.f);
    }
  }
  __syncthreads();

  const float cglast = cg[63];
  if (w == 0) {
    const int l = lane;
    float Tc[64];
#pragma unroll
    for (int i = 0; i < 64; ++i) {
      float v = (i == l) ? 1.f : 0.f;
#pragma unroll
      for (int j = 0; j < i; ++j) v -= bf2f(Bm[i][j]) * Tc[j];
      Tc[i] = v;
    }
#pragma unroll
    for (int i = 0; i < 64; ++i)
      Tg[(size_t)blockIdx.x * 4096 + i * 64 + l] = f2bf(Tc[i]);
    if (lane == 0) esg[blockIdx.x] = __expf(cglast);
  } else {
    const int t2 = tid - 64;
    for (int idx = t2; idx < 2048; idx += 448) {
      const int i = idx >> 5;
      const int dk = (idx & 31) * 4;
      const int boff = i * 256 + ((dk * 2) ^ ((i & 7) << 4));
      const ushort4 kq = *(const ushort4*)((char*)Kb + boff);
      const ushort4 qq = *(const ushort4*)((char*)Qb + boff);
      const float ei = __expf(cg[i]);
      const float wi = btl[i] * ei;
      ushort4 wo = {f2bf(wi * bf2f(kq.x)), f2bf(wi * bf2f(kq.y)),
                    f2bf(wi * bf2f(kq.z)), f2bf(wi * bf2f(kq.w))};
      ushort4 qo = {f2bf(ei * bf2f(qq.x)), f2bf(ei * bf2f(qq.y)),
                    f2bf(ei * bf2f(qq.z)), f2bf(ei * bf2f(qq.w))};
      *(ushort4*)&Wtg[(size_t)blockIdx.x * 8192 + i * 128 + dk] = wo;
      *(ushort4*)&Qtg[(size_t)blockIdx.x * 8192 + i * 128 + dk] = qo;

      float wv[4][4];
#pragma unroll
      for (int x = 0; x < 4; ++x) {
        const float4 a = *(const float4*)&conv_w[(2048 + h * 128 + dk + x) * 4];
        wv[x][0] = a.x; wv[x][1] = a.y; wv[x][2] = a.z; wv[x][3] = a.w;
      }
      float4 va = {0.f, 0.f, 0.f, 0.f};
#pragma unroll
      for (int j = 0; j < 4; ++j) {
        const float4 xv = *(const float4*)&raw[i + j][dk];
        va.x = fmaf(wv[0][j], xv.x, va.x); va.y = fmaf(wv[1][j], xv.y, va.y);
        va.z = fmaf(wv[2][j], xv.z, va.z); va.w = fmaf(wv[3][j], xv.w, va.w);
      }
      float4 bv4;
      bv4.x = btl[i] * va.x / (1.f + __expf(-va.x));
      bv4.y = btl[i] * va.y / (1.f + __expf(-va.y));
      bv4.z = btl[i] * va.z / (1.f + __expf(-va.z));
      bv4.w = btl[i] * va.w / (1.f + __expf(-va.w));
      *(float4*)&bvg[(size_t)blockIdx.x * 8192 + i * 128 + dk] = bv4;
    }
    for (int lin = t2; lin < 8192; lin += 448) {
      const int dk = lin >> 6, i = lin & 63;
      const unsigned short kraw =
          *(const unsigned short*)((char*)Kb + i * 256 + ((dk * 2) ^ ((i & 7) << 4)));
      Khg[(size_t)blockIdx.x * 8192 + lin] = f2bf(__expf(cglast - cg[i]) * bf2f(kraw));
    }
  }
#undef ISSUE
#undef WRITE
#undef CONV_TO
}
#undef NT

// ---------------------------------------------------------------------------
// scan_rec: serial over 16 chunks, (h, dv-block) parallel,
// h = bid&15 -> same-head blocks share one XCD's L2; reg-prefetch 2 sets.
// ---------------------------------------------------------------------------
struct SFrags {
  short8 wf[4];
  short8 tf[2];
  short8 qf[4];
  short8 gf[2];
  short8 kh[2][2];
  float  bv[4];
  float  es;
};

__device__ __forceinline__ void sload(SFrags& F,
    const unsigned short* __restrict__ Tg, const unsigned short* __restrict__ Gg,
    const unsigned short* __restrict__ Wtg, const unsigned short* __restrict__ Qtg,
    const unsigned short* __restrict__ Khg, const float* __restrict__ bvg,
    const float* __restrict__ esg,
    size_t base, int w, int lr, int lk, int dv0) {
  const unsigned short* T_  = Tg  + base * 4096;
  const unsigned short* G_  = Gg  + base * 4096;
  const unsigned short* W_  = Wtg + base * 8192;
  const unsigned short* Q_  = Qtg + base * 8192;
  const unsigned short* Kh_ = Khg + base * 8192;
  const float* bv_ = bvg + base * 8192;
#pragma unroll
  for (int ks = 0; ks < 4; ++ks) {
    F.wf[ks] = *(const short8*)(W_ + (16 * w + lr) * 128 + ks * 32 + lk * 8);
    F.qf[ks] = *(const short8*)(Q_ + (16 * w + lr) * 128 + ks * 32 + lk * 8);
  }
#pragma unroll
  for (int ks = 0; ks < 2; ++ks) {
    F.tf[ks]    = *(const short8*)(T_ + (16 * w + lr) * 64 + ks * 32 + lk * 8);
    F.gf[ks]    = *(const short8*)(G_ + (16 * w + lr) * 64 + ks * 32 + lk * 8);
    F.kh[0][ks] = *(const short8*)(Kh_ + (32 * w + lr) * 64 + ks * 32 + lk * 8);
    F.kh[1][ks] = *(const short8*)(Kh_ + (32 * w + 16 + lr) * 64 + ks * 32 + lk * 8);
  }
#pragma unroll
  for (int r = 0; r < 4; ++r)
    F.bv[r] = bv_[(16 * w + lk * 4 + r) * 128 + dv0 + lr];
  F.es = esg[base];
}

__global__ __launch_bounds__(256) void scan_rec(
    const unsigned short* __restrict__ Tg, const unsigned short* __restrict__ Gg,
    const unsigned short* __restrict__ Wtg, const unsigned short* __restrict__ Qtg,
    const unsigned short* __restrict__ Khg, const float* __restrict__ bvg,
    const float* __restrict__ esg, float* __restrict__ obuf) {
  const int h   = blockIdx.x & 15;
  const int dvb = blockIdx.x >> 4;
  const int dv0 = dvb * 16;
  const int tid = threadIdx.x;
  const int lane = tid & 63;
  const int w   = tid >> 6;
  const int lr  = lane & 15;
  const int lk  = lane >> 4;

  __shared__ unsigned short Sb[16][136];
  __shared__ unsigned short Ub[16][72];
  __shared__ unsigned short Db[16][72];

  for (int n = tid; n < 16 * 136 / 2; n += 256) ((unsigned int*)Sb)[n] = 0u;

  f32x4 sacc0 = {0.f, 0.f, 0.f, 0.f};
  f32x4 sacc1 = {0.f, 0.f, 0.f, 0.f};

  SFrags fA, fB;
  sload(fA, Tg, Gg, Wtg, Qtg, Khg, bvg, esg, (size_t)h * 16, w, lr, lk, dv0);
  __syncthreads();

#define SCAN_CHUNK(F, c)                                                      \
  {                                                                           \
    short8 sb[4];                                                             \
    _Pragma("unroll")                                                         \
    for (int ks = 0; ks < 4; ++ks)                                            \
      sb[ks] = *(const short8*)(&Sb[lr][ks * 32 + lk * 8]);                   \
    f32x4 au = {0.f, 0.f, 0.f, 0.f};                                          \
    _Pragma("unroll")                                                         \
    for (int ks = 0; ks < 4; ++ks)                                            \
      au = __builtin_amdgcn_mfma_f32_16x16x32_bf16(F.wf[ks], sb[ks], au, 0, 0, 0); \
    {                                                                         \
      ushort4 pk;                                                             \
      _Pragma("unroll")                                                       \
      for (int r = 0; r < 4; ++r)                                             \
        ((unsigned short*)&pk)[r] = f2bf(F.bv[r] - au[r]);                    \
      *(ushort4*)&Ub[lr][16 * w + lk * 4] = pk;                               \
    }                                                                         \
    __syncthreads();                                                          \
    f32x4 ad = {0.f, 0.f, 0.f, 0.f};                                          \
    _Pragma("unroll")                                                         \
    for (int ks = 0; ks < 2; ++ks) {                                          \
      const short8 ub = *(const short8*)(&Ub[lr][ks * 32 + lk * 8]);          \
      ad = __builtin_amdgcn_mfma_f32_16x16x32_bf16(F.tf[ks], ub, ad, 0, 0, 0); \
    }                                                                         \
    {                                                                         \
      ushort4 pk;                                                             \
      _Pragma("unroll")                                                       \
      for (int r = 0; r < 4; ++r) ((unsigned short*)&pk)[r] = f2bf(ad[r]);    \
      *(ushort4*)&Db[lr][16 * w + lk * 4] = pk;                               \
    }                                                                         \
    __syncthreads();                                                          \
    short8 dbf[2];                                                            \
    _Pragma("unroll")                                                         \
    for (int ks = 0; ks < 2; ++ks)                                            \
      dbf[ks] = *(const short8*)(&Db[lr][ks * 32 + lk * 8]);                  \
    f32x4 ao = {0.f, 0.f, 0.f, 0.f};                                          \
    _Pragma("unroll")                                                         \
    for (int ks = 0; ks < 4; ++ks)                                            \
      ao = __builtin_amdgcn_mfma_f32_16x16x32_bf16(F.qf[ks], sb[ks], ao, 0, 0, 0); \
    _Pragma("unroll")                                                         \
    for (int ks = 0; ks < 2; ++ks)                                            \
      ao = __builtin_amdgcn_mfma_f32_16x16x32_bf16(F.gf[ks], dbf[ks], ao, 0, 0, 0); \
    _Pragma("unroll")                                                         \
    for (int r = 0; r < 4; ++r) {                                             \
      const int i = 16 * w + lk * 4 + r;                                      \
      obuf[((size_t)((c) * 64 + i) * 16 + h) * 128 + dv0 + lr] = ao[r];       \
    }                                                                         \
    sacc0 *= F.es;                                                            \
    sacc1 *= F.es;                                                            \
    _Pragma("unroll")                                                         \
    for (int ks = 0; ks < 2; ++ks) {                                          \
      sacc0 = __builtin_amdgcn_mfma_f32_16x16x32_bf16(F.kh[0][ks], dbf[ks], sacc0, 0, 0, 0); \
      sacc1 = __builtin_amdgcn_mfma_f32_16x16x32_bf16(F.kh[1][ks], dbf[ks], sacc1, 0, 0, 0); \
    }                                                                         \
    {                                                                         \
      ushort4 p0, p1;                                                         \
      _Pragma("unroll")                                                       \
      for (int r = 0; r < 4; ++r) {                                           \
        ((unsigned short*)&p0)[r] = f2bf(sacc0[r]);                           \
        ((unsigned short*)&p1)[r] = f2bf(sacc1[r]);                           \
      }                                                                       \
      *(ushort4*)&Sb[lr][32 * w + lk * 4] = p0;                               \
      *(ushort4*)&Sb[lr][32 * w + 16 + lk * 4] = p1;                          \
    }                                                                         \
    __syncthreads();                                                          \
  }

  for (int c = 0; c < 16; c += 2) {
    const int c1 = (c + 1 < 15) ? c + 1 : 15;
    const int c2 = (c + 2 < 15) ? c + 2 : 15;
    sload(fB, Tg, Gg, Wtg, Qtg, Khg, bvg, esg, (size_t)h * 16 + c1, w, lr, lk, dv0);
    SCAN_CHUNK(fA, c);
    sload(fA, Tg, Gg, Wtg, Qtg, Khg, bvg, esg, (size_t)h * 16 + c2, w, lr, lk, dv0);
    SCAN_CHUNK(fB, c + 1);
  }
#undef SCAN_CHUNK
}

// ---------------------------------------------------------------------------
// gated RMSNorm -> bf16. 1024 blocks x 256 thr.
// ---------------------------------------------------------------------------
__global__ __launch_bounds__(256) void rmsnorm_kernel(const float* __restrict__ obuf,
                                                      const float* __restrict__ qkvz,
                                                      const float* __restrict__ nw,
                                                      unsigned short* __restrict__ on) {
  const int s    = blockIdx.x;
  const int half = threadIdx.x >> 7;
  const int d    = threadIdx.x & 127;
  __shared__ float red[4];

  for (int it = 0; it < 8; ++it) {
    const int vh = it * 2 + half;
    const float x = obuf[((size_t)s * 16 + vh) * 128 + d];
    float ss = x * x;
#pragma unroll
    for (int m = 1; m < 64; m <<= 1) ss += __shfl_xor(ss, m);
    if ((threadIdx.x & 63) == 0) red[threadIdx.x >> 6] = ss;
    __syncthreads();
    const float tot = red[half * 2] + red[half * 2 + 1];

    const float z = qkvz[(size_t)s * NQKVZ + (vh >> 1) * 768 + 512 + (vh & 1) * 128 + d];
    const float y = x * rsqrtf(tot * (1.f / 128.f) + 1e-6f) * nw[d] *
                    (z / (1.f + expf(-z)));
    on[(size_t)s * 2048 + vh * 128 + d] = f2bf(y);
    __syncthreads();
  }
}

// ---------------------------------------------------------------------------
extern "C" void kernel_launch(void* const* d_in, const int* in_sizes, int n_in,
                              void* d_out, int out_size, void* d_ws, size_t ws_size,
                              hipStream_t stream) {
  const float* hid     = (const float*)d_in[0];
  const float* W_qkvz  = (const float*)d_in[1];
  const float* W_ba    = (const float*)d_in[2];
  const float* conv_w  = (const float*)d_in[3];
  const float* dt_bias = (const float*)d_in[4];
  const float* A_log   = (const float*)d_in[5];
  const float* norm_w  = (const float*)d_in[6];
  const float* W_out   = (const float*)d_in[7];
  float* out = (float*)d_out;

  char* ws = (char*)d_ws;
  float* qkvz = (float*)ws;                 ws += (size_t)SEQ * NQKVZ * 4;   // 24 MB
  char* region2 = ws;                       ws += (size_t)HID * NQKVZ * 2;   // 24 MB
  unsigned short* W1t = (unsigned short*)region2;
  float* obuf = (float*)(region2 + 16777216);
  unsigned short* Xb = (unsigned short*)ws; ws += (size_t)SEQ * HID * 2;     // 4 MB
  unsigned short* on_bf = Xb;
  unsigned short* W2t = (unsigned short*)ws; ws += (size_t)HID * HID * 2;    // 8 MB
  float* gbuf = (float*)ws;                  ws += (size_t)SEQ * 16 * 4;
  float* bet  = (float*)ws;                  ws += (size_t)SEQ * 16 * 4;
  unsigned short* Tg  = (unsigned short*)ws; ws += (size_t)256 * 4096 * 2;
  unsigned short* Gg  = (unsigned short*)ws; ws += (size_t)256 * 4096 * 2;
  unsigned short* Wtg = (unsigned short*)ws; ws += (size_t)256 * 8192 * 2;
  unsigned short* Qtg = (unsigned short*)ws; ws += (size_t)256 * 8192 * 2;
  unsigned short* Khg = (unsigned short*)ws; ws += (size_t)256 * 8192 * 2;
  float* bvg          = (float*)ws;          ws += (size_t)256 * 8192 * 4;
  float* esg          = (float*)ws;          ws += 256 * 4;
  float* Wbt          = (float*)ws;          ws += (size_t)32 * HID * 4;     // 256 KB

  cast_bf16<<<dim3(SEQ * HID / 1024), 256, 0, stream>>>(hid, Xb, SEQ * HID);
  transpose_cast2<<<dim3(128, 32), 256, 0, stream>>>(W_qkvz, W1t, W_out, W2t);
  transpose_f32<<<dim3(HID / 32), 256, 0, stream>>>(W_ba, Wbt);
  ba_kernel<<<dim3(SEQ / 4), 256, 0, stream>>>(hid, Wbt, A_log, dt_bias, gbuf, bet);
  // qkvz = X @ W_qkvz  (64x128 tile, BK=64 -> 768 blocks = 3/CU)
  gemm_bf16<2, 4, 2><<<dim3(NQKVZ / 128, SEQ / 64), 256, 0, stream>>>(Xb, W1t, qkvz,
                                                                      SEQ, NQKVZ, HID);
  chunk_prep<<<dim3(256), 512, 0, stream>>>(qkvz, conv_w, gbuf, bet,
                                            Tg, Gg, Wtg, Qtg, Khg, bvg, esg);
  scan_rec<<<dim3(128), 256, 0, stream>>>(Tg, Gg, Wtg, Qtg, Khg, bvg, esg, obuf);
  rmsnorm_kernel<<<dim3(SEQ), 256, 0, stream>>>(obuf, qkvz, norm_w, on_bf);
  // out = on @ W_out  (64x64 tile, BK=64 -> 512 blocks = 2/CU)
  gemm_bf16<2, 2, 2><<<dim3(HID / 64, SEQ / 64), 256, 0, stream>>>(on_bf, W2t, out,
                                                                   SEQ, HID, HID);
}

// Round 15
// 171.178 us; speedup vs baseline: 1.0765x; 1.0138x over previous
//
#include <hip/hip_runtime.h>
#include <hip/hip_bf16.h>
#include <math.h>

// Qwen3-Next GatedDeltaNet, B=1, S=1024, HIDDEN=2048
// H_K=8, H_V=16, DK=DV=128, KDIM=1024, VDIM=2048, CONV_DIM=4096, KS=4
// Chunked delta rule: C=64, 16 chunks. qkvz kept in bf16; chunk_prep v7
// stages q+k+v in ONE latency exposure, 3 barriers total.

#define SEQ 1024
#define HID 2048
#define NQKVZ 6144

typedef __attribute__((ext_vector_type(8))) short short8;
typedef __attribute__((ext_vector_type(4))) float f32x4;

__device__ __forceinline__ unsigned short f2bf(float f) {
  __hip_bfloat16 h = __float2bfloat16(f);
  return *reinterpret_cast<unsigned short*>(&h);
}
__device__ __forceinline__ float bf2f(unsigned short u) {
  unsigned int x = ((unsigned int)u) << 16;
  return __int_as_float(x);
}

// async global->LDS, 16B per lane (dest = wave-uniform base + lane*16)
typedef __attribute__((address_space(3))) void lds_void;
typedef const __attribute__((address_space(1))) void g_void;
__device__ __forceinline__ void gload16(const void* g, void* l) {
  __builtin_amdgcn_global_load_lds((g_void*)g, (lds_void*)l, 16, 0, 0);
}

// ---------------------------------------------------------------------------
// elementwise f32 -> bf16 cast
// ---------------------------------------------------------------------------
__global__ __launch_bounds__(256) void cast_bf16(const float* __restrict__ in,
                                                 unsigned short* __restrict__ out,
                                                 int n) {
  const int i = (blockIdx.x * 256 + threadIdx.x) * 4;
  if (i < n) {
    const float4 v = *(const float4*)&in[i];
    ushort4 o;
    o.x = f2bf(v.x); o.y = f2bf(v.y); o.z = f2bf(v.z); o.w = f2bf(v.w);
    *(ushort4*)&out[i] = o;
  }
}

// ---------------------------------------------------------------------------
// merged W_qkvz / W_out transpose-cast: 64x64 tiles, float4 I/O.
// ---------------------------------------------------------------------------
__global__ __launch_bounds__(256) void transpose_cast2(const float* __restrict__ W1,
                                                       unsigned short* __restrict__ W1t,
                                                       const float* __restrict__ W2,
                                                       unsigned short* __restrict__ W2t) {
  __shared__ float tile[64][65];
  int bx = blockIdx.x;
  const float* W;
  unsigned short* Wt;
  int N;
  if (bx < 96) { W = W1; Wt = W1t; N = NQKVZ; }
  else         { W = W2; Wt = W2t; N = HID; bx -= 96; }
  const int n0 = bx * 64, k0 = blockIdx.y * 64;
  const int tc = (threadIdx.x & 15) * 4;
  const int tr = threadIdx.x >> 4;

#pragma unroll
  for (int rr = 0; rr < 64; rr += 16) {
    const float4 v = *(const float4*)&W[(size_t)(k0 + tr + rr) * N + n0 + tc];
    *(float4*)&tile[tr + rr][tc] = v;
  }
  __syncthreads();
#pragma unroll
  for (int rr = 0; rr < 64; rr += 16) {
    const int r = tr + rr;
    ushort4 o;
    o.x = f2bf(tile[tc + 0][r]);
    o.y = f2bf(tile[tc + 1][r]);
    o.z = f2bf(tile[tc + 2][r]);
    o.w = f2bf(tile[tc + 3][r]);
    *(ushort4*)&Wt[(size_t)(n0 + r) * HID + k0 + tc] = o;
  }
}

// ---------------------------------------------------------------------------
// W_ba[2048][32] f32 -> Wbt[32][2048] f32
// ---------------------------------------------------------------------------
__global__ __launch_bounds__(256) void transpose_f32(const float* __restrict__ W,
                                                     float* __restrict__ Wt) {
  __shared__ float tile[32][33];
  const int k0 = blockIdx.x * 32;
  const int tx = threadIdx.x & 31, ty = threadIdx.x >> 5;
#pragma unroll
  for (int r = 0; r < 32; r += 8)
    tile[ty + r][tx] = W[(size_t)(k0 + ty + r) * 32 + tx];
  __syncthreads();
#pragma unroll
  for (int r = 0; r < 32; r += 8)
    Wt[(size_t)(ty + r) * HID + k0 + tx] = tile[tx][ty + r];
}

// ---------------------------------------------------------------------------
// ba: split-K GEMV vs Wbt[32][2048] f32, fused activations.
// ---------------------------------------------------------------------------
__global__ __launch_bounds__(256) void ba_kernel(const float* __restrict__ X,
                                                 const float* __restrict__ Wbt,
                                                 const float* __restrict__ A_log,
                                                 const float* __restrict__ dt_bias,
                                                 float* __restrict__ gbuf,
                                                 float* __restrict__ bet) {
  const int col = threadIdx.x & 31;
  const int kg  = threadIdx.x >> 5;
  const int s0  = blockIdx.x * 4;
  const float* wp = Wbt + (size_t)col * HID + kg * 256;
  const float* xp = X + (size_t)s0 * HID + kg * 256;

  float a0 = 0.f, a1 = 0.f, a2 = 0.f, a3 = 0.f;
  for (int kk = 0; kk < 256; kk += 4) {
    const float4 w4 = *(const float4*)&wp[kk];
    const float4 x0 = *(const float4*)&xp[kk];
    const float4 x1 = *(const float4*)&xp[kk + HID];
    const float4 x2 = *(const float4*)&xp[kk + 2 * HID];
    const float4 x3 = *(const float4*)&xp[kk + 3 * HID];
    a0 += x0.x * w4.x + x0.y * w4.y + x0.z * w4.z + x0.w * w4.w;
    a1 += x1.x * w4.x + x1.y * w4.y + x1.z * w4.z + x1.w * w4.w;
    a2 += x2.x * w4.x + x2.y * w4.y + x2.z * w4.z + x2.w * w4.w;
    a3 += x3.x * w4.x + x3.y * w4.y + x3.z * w4.z + x3.w * w4.w;
  }
  __shared__ float red[4][32][9];
  red[0][col][kg] = a0;
  red[1][col][kg] = a1;
  red[2][col][kg] = a2;
  red[3][col][kg] = a3;
  __syncthreads();
  if (threadIdx.x < 128) {
    const int r = threadIdx.x >> 5;
    const int c = threadIdx.x & 31;
    float acc = 0.f;
#pragma unroll
    for (int g = 0; g < 8; ++g) acc += red[r][c][g];
    const int s = s0 + r;
    const int hk = c >> 2, j = c & 3;
    if (j < 2) {
      bet[s * 16 + hk * 2 + j] = 1.f / (1.f + expf(-acc));
    } else {
      const int vh = hk * 2 + (j - 2);
      const float x = acc + dt_bias[vh];
      const float sp = (x > 20.f) ? x : log1pf(expf(x));
      gbuf[s * 16 + vh] = -expf(A_log[vh]) * sp;
    }
  }
}

// ---------------------------------------------------------------------------
// bf16 MFMA GEMM: C = A @ Bt^T. OUTBF selects bf16 or f32 C.
// Block tile (32*MF)x(32*NF), BK=32*KF, 4 waves (2x2).
// ---------------------------------------------------------------------------
#define SWZ(row) ((KF == 1) ? (((row) >> 1) & 3) : ((row) & 7))

template <int MF, int NF, int KF, bool OUTBF>
__global__ __launch_bounds__(256) void gemm_bf16(const unsigned short* __restrict__ A,
                                                 const unsigned short* __restrict__ Bt,
                                                 void* __restrict__ Cv,
                                                 int M, int N, int K) {
  constexpr int BM = 32 * MF, BN = 32 * NF, BK = 32 * KF;
  constexpr int RB  = BK * 2;
  constexpr int APW = (BM * KF / 16) / 4;
  constexpr int BPW = (BN * KF / 16) / 4;
  constexpr int RPG = 16 / KF;
  __shared__ unsigned short As[2][BM * BK];
  __shared__ unsigned short Bs[2][BN * BK];

  const int tid  = threadIdx.x;
  const int lane = tid & 63;
  const int w    = tid >> 6;
  const int wm   = w >> 1, wn = w & 1;
  const int row0 = blockIdx.y * BM, col0 = blockIdx.x * BN;

  const int lrow  = (KF == 1) ? (lane >> 2) : (lane >> 3);
  const int lslot = lane & (4 * KF - 1);
  const int arow  = lane & 15;

  f32x4 acc[MF][NF];
#pragma unroll
  for (int m = 0; m < MF; ++m)
#pragma unroll
    for (int n = 0; n < NF; ++n) acc[m][n] = (f32x4){0.f, 0.f, 0.f, 0.f};

  auto stage = [&](int bi, int kt) {
    const int ko = kt * BK;
#pragma unroll
    for (int u = 0; u < APW; ++u) {
      const int gu = w * APW + u;
      const int row = gu * RPG + lrow;
      const int sg = lslot ^ SWZ(row);
      gload16(A + (size_t)(row0 + row) * K + ko + sg * 8,
              (char*)As[bi] + gu * 1024 + lane * 16);
    }
#pragma unroll
    for (int u = 0; u < BPW; ++u) {
      const int gu = w * BPW + u;
      const int row = gu * RPG + lrow;
      const int sg = lslot ^ SWZ(row);
      gload16(Bt + (size_t)(col0 + row) * K + ko + sg * 8,
              (char*)Bs[bi] + gu * 1024 + lane * 16);
    }
  };

  stage(0, 0);
  __syncthreads();

  int cur = 0;
  const int nk = K / BK;
  for (int kt = 0; kt < nk; ++kt) {
    if (kt + 1 < nk) stage(cur ^ 1, kt + 1);

    const char* asb = (const char*)As[cur];
    const char* bsb = (const char*)Bs[cur];
    short8 af[MF][KF], bf[NF][KF];
#pragma unroll
    for (int m = 0; m < MF; ++m)
#pragma unroll
      for (int kk = 0; kk < KF; ++kk) {
        const int row = wm * (16 * MF) + m * 16 + arow;
        const int slot = kk * 4 + (lane >> 4);
        af[m][kk] = *(const short8*)(asb + row * RB + ((slot ^ SWZ(row)) * 16));
      }
#pragma unroll
    for (int n = 0; n < NF; ++n)
#pragma unroll
      for (int kk = 0; kk < KF; ++kk) {
        const int row = wn * (16 * NF) + n * 16 + arow;
        const int slot = kk * 4 + (lane >> 4);
        bf[n][kk] = *(const short8*)(bsb + row * RB + ((slot ^ SWZ(row)) * 16));
      }
#pragma unroll
    for (int m = 0; m < MF; ++m)
#pragma unroll
      for (int n = 0; n < NF; ++n)
#pragma unroll
        for (int kk = 0; kk < KF; ++kk)
          acc[m][n] = __builtin_amdgcn_mfma_f32_16x16x32_bf16(af[m][kk], bf[n][kk],
                                                              acc[m][n], 0, 0, 0);

    __syncthreads();
    cur ^= 1;
  }

#pragma unroll
  for (int m = 0; m < MF; ++m)
#pragma unroll
    for (int n = 0; n < NF; ++n) {
      const int r0 = row0 + wm * (16 * MF) + m * 16 + (lane >> 4) * 4;
      const int c  = col0 + wn * (16 * NF) + n * 16 + (lane & 15);
#pragma unroll
      for (int r = 0; r < 4; ++r) {
        if (OUTBF)
          ((unsigned short*)Cv)[(size_t)(r0 + r) * N + c] = f2bf(acc[m][n][r]);
        else
          ((float*)Cv)[(size_t)(r0 + r) * N + c] = acc[m][n][r];
      }
    }
}

// ---------------------------------------------------------------------------
// chunk_prep v7: qkvz bf16 input. ONE staging burst for q+k+v (15 ushort4
// loads in flight per thread), 3 barriers total. conv-q + conv-k
// back-to-back (raw read-only). Waves 0-3 KK^T, 4-7 QK^T; wave 0 reg-solve
// || 7-wave epilogue (v-conv from rawv).
// ---------------------------------------------------------------------------
#define NT 512
__global__ __launch_bounds__(NT) void chunk_prep(
    const unsigned short* __restrict__ qkvz, const float* __restrict__ conv_w,
    const float* __restrict__ gbuf, const float* __restrict__ bet,
    unsigned short* __restrict__ Tg, unsigned short* __restrict__ Gg,
    unsigned short* __restrict__ Wtg, unsigned short* __restrict__ Qtg,
    unsigned short* __restrict__ Khg, float* __restrict__ bvg,
    float* __restrict__ esg) {
  const int h  = blockIdx.x >> 4;
  const int c  = blockIdx.x & 15;
  const int hk = h >> 1;
  const int tid = threadIdx.x;
  const int lane = tid & 63;
  const int w    = tid >> 6;
  const int lr   = lane & 15;
  const int lk   = lane >> 4;

  __shared__ unsigned short rawq[67 * 132];  // 17.7 KB bf16, padded rows
  __shared__ unsigned short rawk[67 * 132];
  __shared__ unsigned short rawv[67 * 132];
  __shared__ unsigned short Kb[64 * 128];    // swizzled rows of 256B
  __shared__ unsigned short Qb[64 * 128];
  __shared__ unsigned short Bm[64][64];
  __shared__ float cg[64];
  __shared__ float btl[64];

  const int s0 = c * 64;
  const int qcol0 = hk * 768;
  const int kcol0 = hk * 768 + 128;
  const int vcol0 = hk * 768 + 256 + (h & 1) * 128;

  // ---- single staging burst: issue ALL q,k,v loads, then write
  ushort4 rq[5], rk[5], rv[5];
#pragma unroll
  for (int ii = 0; ii < 5; ++ii) {
    const int idx = tid + NT * ii;
    if (idx < 67 * 32) {
      const int r = idx >> 5, cq = (idx & 31) * 4;
      const int sr = s0 - 3 + r;
      if (sr >= 0) {
        rq[ii] = *(const ushort4*)&qkvz[(size_t)sr * NQKVZ + qcol0 + cq];
        rk[ii] = *(const ushort4*)&qkvz[(size_t)sr * NQKVZ + kcol0 + cq];
        rv[ii] = *(const ushort4*)&qkvz[(size_t)sr * NQKVZ + vcol0 + cq];
      } else {
        rq[ii] = (ushort4){0, 0, 0, 0};
        rk[ii] = (ushort4){0, 0, 0, 0};
        rv[ii] = (ushort4){0, 0, 0, 0};
      }
    }
  }
  if (tid < 64) {
    float g = gbuf[(s0 + tid) * 16 + h];
#pragma unroll
    for (int d = 1; d < 64; d <<= 1) {
      const float o = __shfl_up(g, d);
      if (tid >= d) g += o;
    }
    cg[tid] = g;
    btl[tid] = bet[(s0 + tid) * 16 + h];
  }
#pragma unroll
  for (int ii = 0; ii < 5; ++ii) {
    const int idx = tid + NT * ii;
    if (idx < 67 * 32) {
      const int r = idx >> 5, cq = (idx & 31) * 4;
      *(ushort4*)&rawq[r * 132 + cq] = rq[ii];
      *(ushort4*)&rawk[r * 132 + cq] = rk[ii];
      *(ushort4*)&rawv[r * 132 + cq] = rv[ii];
    }
  }
  __syncthreads();  // barrier 1: raw + cg/btl ready

#define CONV_TO(dst, rawsrc, wbase, isq)                                      \
  for (int n = 0; n < 4; ++n) {                                               \
    const int idx = tid + NT * n;                                             \
    const int row = idx >> 5;                                                 \
    const int col = (idx & 31) * 4;                                           \
    float wgt[4][4];                                                          \
    _Pragma("unroll")                                                         \
    for (int x = 0; x < 4; ++x) {                                             \
      const float4 a = *(const float4*)&conv_w[((wbase) + hk * 128 + col + x) * 4]; \
      wgt[x][0] = a.x; wgt[x][1] = a.y; wgt[x][2] = a.z; wgt[x][3] = a.w;     \
    }                                                                         \
    float4 ac = {0.f, 0.f, 0.f, 0.f};                                         \
    _Pragma("unroll")                                                         \
    for (int j = 0; j < 4; ++j) {                                             \
      const ushort4 xr4 = *(const ushort4*)&rawsrc[(row + j) * 132 + col];    \
      ac.x = fmaf(wgt[0][j], bf2f(xr4.x), ac.x);                              \
      ac.y = fmaf(wgt[1][j], bf2f(xr4.y), ac.y);                              \
      ac.z = fmaf(wgt[2][j], bf2f(xr4.z), ac.z);                              \
      ac.w = fmaf(wgt[3][j], bf2f(xr4.w), ac.w);                              \
    }                                                                         \
    float4 y;                                                                 \
    y.x = ac.x / (1.f + __expf(-ac.x)); y.y = ac.y / (1.f + __expf(-ac.y));   \
    y.z = ac.z / (1.f + __expf(-ac.z)); y.w = ac.w / (1.f + __expf(-ac.w));   \
    float ss = y.x * y.x + y.y * y.y + y.z * y.z + y.w * y.w;                 \
    _Pragma("unroll")                                                         \
    for (int m = 1; m <= 16; m <<= 1) ss += __shfl_xor(ss, m);                \
    float sc = rsqrtf(ss + 1e-6f);                                            \
    if (isq) sc *= 0.08838834764831845f;                                      \
    const int boff = row * 256 + ((col * 2) ^ ((row & 7) << 4));              \
    ushort4 o = {f2bf(y.x * sc), f2bf(y.y * sc), f2bf(y.z * sc), f2bf(y.w * sc)}; \
    *(ushort4*)((char*)(dst) + boff) = o;                                     \
  }

  CONV_TO(Qb, rawq, 0, true);
  CONV_TO(Kb, rawk, 1024, false);
  __syncthreads();  // barrier 2: Kb/Qb ready

  // ---- dots via MFMA: waves 0-3 KK^T, waves 4-7 QK^T
  const bool isK = (w < 4);
  const int w4 = w & 3;
  f32x4 dacc[4];
#pragma unroll
  for (int ct = 0; ct < 4; ++ct) dacc[ct] = (f32x4){0.f, 0.f, 0.f, 0.f};
  {
    const int rowA = 16 * w4 + lr;
    const int swA  = (rowA & 7) << 4;
    const char* Ab = isK ? (const char*)Kb : (const char*)Qb;
#pragma unroll
    for (int ks = 0; ks < 4; ++ks) {
      const int kb = ks * 64 + lk * 16;
      const short8 a = *(const short8*)(Ab + rowA * 256 + (kb ^ swA));
#pragma unroll
      for (int ct = 0; ct < 4; ++ct) {
        const int rowB = ct * 16 + lr;
        const short8 bK = *(const short8*)((char*)Kb + rowB * 256 + (kb ^ ((rowB & 7) << 4)));
        dacc[ct] = __builtin_amdgcn_mfma_f32_16x16x32_bf16(a, bK, dacc[ct], 0, 0, 0);
      }
    }
  }
#pragma unroll
  for (int ct = 0; ct < 4; ++ct) {
#pragma unroll
    for (int r = 0; r < 4; ++r) {
      const int i = 16 * w4 + lk * 4 + r;
      const int j = ct * 16 + lr;
      const float e = __expf(cg[i] - cg[j]);
      if (isK) Bm[i][j] = f2bf((j < i) ? btl[i] * e * dacc[ct][r] : 0.f);
      else     Gg[(size_t)blockIdx.x * 4096 + i * 64 + j] =
                   f2bf((j <= i) ? e * dacc[ct][r] : 0.f);
    }
  }
  __syncthreads();  // barrier 3: Bm ready

  // ---- wave 0: register triangular solve; waves 1-7: operand outputs
  const float cglast = cg[63];
  if (w == 0) {
    const int l = lane;
    float Tc[64];
#pragma unroll
    for (int i = 0; i < 64; ++i) {
      float v = (i == l) ? 1.f : 0.f;
#pragma unroll
      for (int j = 0; j < i; ++j) v -= bf2f(Bm[i][j]) * Tc[j];
      Tc[i] = v;
    }
#pragma unroll
    for (int i = 0; i < 64; ++i)
      Tg[(size_t)blockIdx.x * 4096 + i * 64 + l] = f2bf(Tc[i]);
    if (lane == 0) esg[blockIdx.x] = __expf(cglast);
  } else {
    const int t2 = tid - 64;
    for (int idx = t2; idx < 2048; idx += 448) {
      const int i = idx >> 5;
      const int dk = (idx & 31) * 4;
      const int boff = i * 256 + ((dk * 2) ^ ((i & 7) << 4));
      const ushort4 kq = *(const ushort4*)((char*)Kb + boff);
      const ushort4 qq = *(const ushort4*)((char*)Qb + boff);
      const float ei = __expf(cg[i]);
      const float wi = btl[i] * ei;
      ushort4 wo = {f2bf(wi * bf2f(kq.x)), f2bf(wi * bf2f(kq.y)),
                    f2bf(wi * bf2f(kq.z)), f2bf(wi * bf2f(kq.w))};
      ushort4 qo = {f2bf(ei * bf2f(qq.x)), f2bf(ei * bf2f(qq.y)),
                    f2bf(ei * bf2f(qq.z)), f2bf(ei * bf2f(qq.w))};
      *(ushort4*)&Wtg[(size_t)blockIdx.x * 8192 + i * 128 + dk] = wo;
      *(ushort4*)&Qtg[(size_t)blockIdx.x * 8192 + i * 128 + dk] = qo;

      float wv[4][4];
#pragma unroll
      for (int x = 0; x < 4; ++x) {
        const float4 a = *(const float4*)&conv_w[(2048 + h * 128 + dk + x) * 4];
        wv[x][0] = a.x; wv[x][1] = a.y; wv[x][2] = a.z; wv[x][3] = a.w;
      }
      float4 va = {0.f, 0.f, 0.f, 0.f};
#pragma unroll
      for (int j = 0; j < 4; ++j) {
        const ushort4 xv4 = *(const ushort4*)&rawv[(i + j) * 132 + dk];
        va.x = fmaf(wv[0][j], bf2f(xv4.x), va.x);
        va.y = fmaf(wv[1][j], bf2f(xv4.y), va.y);
        va.z = fmaf(wv[2][j], bf2f(xv4.z), va.z);
        va.w = fmaf(wv[3][j], bf2f(xv4.w), va.w);
      }
      float4 bv4;
      bv4.x = btl[i] * va.x / (1.f + __expf(-va.x));
      bv4.y = btl[i] * va.y / (1.f + __expf(-va.y));
      bv4.z = btl[i] * va.z / (1.f + __expf(-va.z));
      bv4.w = btl[i] * va.w / (1.f + __expf(-va.w));
      *(float4*)&bvg[(size_t)blockIdx.x * 8192 + i * 128 + dk] = bv4;
    }
    for (int lin = t2; lin < 8192; lin += 448) {  // layout [dk][i]
      const int dk = lin >> 6, i = lin & 63;
      const unsigned short kraw =
          *(const unsigned short*)((char*)Kb + i * 256 + ((dk * 2) ^ ((i & 7) << 4)));
      Khg[(size_t)blockIdx.x * 8192 + lin] = f2bf(__expf(cglast - cg[i]) * bf2f(kraw));
    }
  }
#undef CONV_TO
}
#undef NT

// ---------------------------------------------------------------------------
// scan_rec: serial over 16 chunks, (h, dv-block) parallel,
// h = bid&15 -> same-head blocks share one XCD's L2; reg-prefetch 2 sets.
// ---------------------------------------------------------------------------
struct SFrags {
  short8 wf[4];
  short8 tf[2];
  short8 qf[4];
  short8 gf[2];
  short8 kh[2][2];
  float  bv[4];
  float  es;
};

__device__ __forceinline__ void sload(SFrags& F,
    const unsigned short* __restrict__ Tg, const unsigned short* __restrict__ Gg,
    const unsigned short* __restrict__ Wtg, const unsigned short* __restrict__ Qtg,
    const unsigned short* __restrict__ Khg, const float* __restrict__ bvg,
    const float* __restrict__ esg,
    size_t base, int w, int lr, int lk, int dv0) {
  const unsigned short* T_  = Tg  + base * 4096;
  const unsigned short* G_  = Gg  + base * 4096;
  const unsigned short* W_  = Wtg + base * 8192;
  const unsigned short* Q_  = Qtg + base * 8192;
  const unsigned short* Kh_ = Khg + base * 8192;
  const float* bv_ = bvg + base * 8192;
#pragma unroll
  for (int ks = 0; ks < 4; ++ks) {
    F.wf[ks] = *(const short8*)(W_ + (16 * w + lr) * 128 + ks * 32 + lk * 8);
    F.qf[ks] = *(const short8*)(Q_ + (16 * w + lr) * 128 + ks * 32 + lk * 8);
  }
#pragma unroll
  for (int ks = 0; ks < 2; ++ks) {
    F.tf[ks]    = *(const short8*)(T_ + (16 * w + lr) * 64 + ks * 32 + lk * 8);
    F.gf[ks]    = *(const short8*)(G_ + (16 * w + lr) * 64 + ks * 32 + lk * 8);
    F.kh[0][ks] = *(const short8*)(Kh_ + (32 * w + lr) * 64 + ks * 32 + lk * 8);
    F.kh[1][ks] = *(const short8*)(Kh_ + (32 * w + 16 + lr) * 64 + ks * 32 + lk * 8);
  }
#pragma unroll
  for (int r = 0; r < 4; ++r)
    F.bv[r] = bv_[(16 * w + lk * 4 + r) * 128 + dv0 + lr];
  F.es = esg[base];
}

__global__ __launch_bounds__(256) void scan_rec(
    const unsigned short* __restrict__ Tg, const unsigned short* __restrict__ Gg,
    const unsigned short* __restrict__ Wtg, const unsigned short* __restrict__ Qtg,
    const unsigned short* __restrict__ Khg, const float* __restrict__ bvg,
    const float* __restrict__ esg, float* __restrict__ obuf) {
  const int h   = blockIdx.x & 15;
  const int dvb = blockIdx.x >> 4;
  const int dv0 = dvb * 16;
  const int tid = threadIdx.x;
  const int lane = tid & 63;
  const int w   = tid >> 6;
  const int lr  = lane & 15;
  const int lk  = lane >> 4;

  __shared__ unsigned short Sb[16][136];
  __shared__ unsigned short Ub[16][72];
  __shared__ unsigned short Db[16][72];

  for (int n = tid; n < 16 * 136 / 2; n += 256) ((unsigned int*)Sb)[n] = 0u;

  f32x4 sacc0 = {0.f, 0.f, 0.f, 0.f};
  f32x4 sacc1 = {0.f, 0.f, 0.f, 0.f};

  SFrags fA, fB;
  sload(fA, Tg, Gg, Wtg, Qtg, Khg, bvg, esg, (size_t)h * 16, w, lr, lk, dv0);
  __syncthreads();

#define SCAN_CHUNK(F, c)                                                      \
  {                                                                           \
    short8 sb[4];                                                             \
    _Pragma("unroll")                                                         \
    for (int ks = 0; ks < 4; ++ks)                                            \
      sb[ks] = *(const short8*)(&Sb[lr][ks * 32 + lk * 8]);                   \
    f32x4 au = {0.f, 0.f, 0.f, 0.f};                                          \
    _Pragma("unroll")                                                         \
    for (int ks = 0; ks < 4; ++ks)                                            \
      au = __builtin_amdgcn_mfma_f32_16x16x32_bf16(F.wf[ks], sb[ks], au, 0, 0, 0); \
    {                                                                         \
      ushort4 pk;                                                             \
      _Pragma("unroll")                                                       \
      for (int r = 0; r < 4; ++r)                                             \
        ((unsigned short*)&pk)[r] = f2bf(F.bv[r] - au[r]);                    \
      *(ushort4*)&Ub[lr][16 * w + lk * 4] = pk;                               \
    }                                                                         \
    __syncthreads();                                                          \
    f32x4 ad = {0.f, 0.f, 0.f, 0.f};                                          \
    _Pragma("unroll")                                                         \
    for (int ks = 0; ks < 2; ++ks) {                                          \
      const short8 ub = *(const short8*)(&Ub[lr][ks * 32 + lk * 8]);          \
      ad = __builtin_amdgcn_mfma_f32_16x16x32_bf16(F.tf[ks], ub, ad, 0, 0, 0); \
    }                                                                         \
    {                                                                         \
      ushort4 pk;                                                             \
      _Pragma("unroll")                                                       \
      for (int r = 0; r < 4; ++r) ((unsigned short*)&pk)[r] = f2bf(ad[r]);    \
      *(ushort4*)&Db[lr][16 * w + lk * 4] = pk;                               \
    }                                                                         \
    __syncthreads();                                                          \
    short8 dbf[2];                                                            \
    _Pragma("unroll")                                                         \
    for (int ks = 0; ks < 2; ++ks)                                            \
      dbf[ks] = *(const short8*)(&Db[lr][ks * 32 + lk * 8]);                  \
    f32x4 ao = {0.f, 0.f, 0.f, 0.f};                                          \
    _Pragma("unroll")                                                         \
    for (int ks = 0; ks < 4; ++ks)                                            \
      ao = __builtin_amdgcn_mfma_f32_16x16x32_bf16(F.qf[ks], sb[ks], ao, 0, 0, 0); \
    _Pragma("unroll")                                                         \
    for (int ks = 0; ks < 2; ++ks)                                            \
      ao = __builtin_amdgcn_mfma_f32_16x16x32_bf16(F.gf[ks], dbf[ks], ao, 0, 0, 0); \
    _Pragma("unroll")                                                         \
    for (int r = 0; r < 4; ++r) {                                             \
      const int i = 16 * w + lk * 4 + r;                                      \
      obuf[((size_t)((c) * 64 + i) * 16 + h) * 128 + dv0 + lr] = ao[r];       \
    }                                                                         \
    sacc0 *= F.es;                                                            \
    sacc1 *= F.es;                                                            \
    _Pragma("unroll")                                                         \
    for (int ks = 0; ks < 2; ++ks) {                                          \
      sacc0 = __builtin_amdgcn_mfma_f32_16x16x32_bf16(F.kh[0][ks], dbf[ks], sacc0, 0, 0, 0); \
      sacc1 = __builtin_amdgcn_mfma_f32_16x16x32_bf16(F.kh[1][ks], dbf[ks], sacc1, 0, 0, 0); \
    }                                                                         \
    {                                                                         \
      ushort4 p0, p1;                                                         \
      _Pragma("unroll")                                                       \
      for (int r = 0; r < 4; ++r) {                                           \
        ((unsigned short*)&p0)[r] = f2bf(sacc0[r]);                           \
        ((unsigned short*)&p1)[r] = f2bf(sacc1[r]);                           \
      }                                                                       \
      *(ushort4*)&Sb[lr][32 * w + lk * 4] = p0;                               \
      *(ushort4*)&Sb[lr][32 * w + 16 + lk * 4] = p1;                          \
    }                                                                         \
    __syncthreads();                                                          \
  }

  for (int c = 0; c < 16; c += 2) {
    const int c1 = (c + 1 < 15) ? c + 1 : 15;
    const int c2 = (c + 2 < 15) ? c + 2 : 15;
    sload(fB, Tg, Gg, Wtg, Qtg, Khg, bvg, esg, (size_t)h * 16 + c1, w, lr, lk, dv0);
    SCAN_CHUNK(fA, c);
    sload(fA, Tg, Gg, Wtg, Qtg, Khg, bvg, esg, (size_t)h * 16 + c2, w, lr, lk, dv0);
    SCAN_CHUNK(fB, c + 1);
  }
#undef SCAN_CHUNK
}

// ---------------------------------------------------------------------------
// gated RMSNorm -> bf16 (z read from bf16 qkvz)
// ---------------------------------------------------------------------------
__global__ __launch_bounds__(256) void rmsnorm_kernel(const float* __restrict__ obuf,
                                                      const unsigned short* __restrict__ qkvz,
                                                      const float* __restrict__ nw,
                                                      unsigned short* __restrict__ on) {
  const int s    = blockIdx.x;
  const int half = threadIdx.x >> 7;
  const int d    = threadIdx.x & 127;
  __shared__ float red[4];

  for (int it = 0; it < 8; ++it) {
    const int vh = it * 2 + half;
    const float x = obuf[((size_t)s * 16 + vh) * 128 + d];
    float ss = x * x;
#pragma unroll
    for (int m = 1; m < 64; m <<= 1) ss += __shfl_xor(ss, m);
    if ((threadIdx.x & 63) == 0) red[threadIdx.x >> 6] = ss;
    __syncthreads();
    const float tot = red[half * 2] + red[half * 2 + 1];

    const float z = bf2f(qkvz[(size_t)s * NQKVZ + (vh >> 1) * 768 + 512 + (vh & 1) * 128 + d]);
    const float y = x * rsqrtf(tot * (1.f / 128.f) + 1e-6f) * nw[d] *
                    (z / (1.f + expf(-z)));
    on[(size_t)s * 2048 + vh * 128 + d] = f2bf(y);
    __syncthreads();
  }
}

// ---------------------------------------------------------------------------
extern "C" void kernel_launch(void* const* d_in, const int* in_sizes, int n_in,
                              void* d_out, int out_size, void* d_ws, size_t ws_size,
                              hipStream_t stream) {
  const float* hid     = (const float*)d_in[0];
  const float* W_qkvz  = (const float*)d_in[1];
  const float* W_ba    = (const float*)d_in[2];
  const float* conv_w  = (const float*)d_in[3];
  const float* dt_bias = (const float*)d_in[4];
  const float* A_log   = (const float*)d_in[5];
  const float* norm_w  = (const float*)d_in[6];
  const float* W_out   = (const float*)d_in[7];
  float* out = (float*)d_out;

  char* ws = (char*)d_ws;
  unsigned short* qkvz = (unsigned short*)ws; ws += (size_t)SEQ * NQKVZ * 2; // 12 MB
  char* region2 = ws;                       ws += (size_t)HID * NQKVZ * 2;   // 24 MB
  unsigned short* W1t = (unsigned short*)region2;
  float* obuf = (float*)(region2 + 16777216);
  unsigned short* Xb = (unsigned short*)ws; ws += (size_t)SEQ * HID * 2;     // 4 MB
  unsigned short* on_bf = Xb;
  unsigned short* W2t = (unsigned short*)ws; ws += (size_t)HID * HID * 2;    // 8 MB
  float* gbuf = (float*)ws;                  ws += (size_t)SEQ * 16 * 4;
  float* bet  = (float*)ws;                  ws += (size_t)SEQ * 16 * 4;
  unsigned short* Tg  = (unsigned short*)ws; ws += (size_t)256 * 4096 * 2;
  unsigned short* Gg  = (unsigned short*)ws; ws += (size_t)256 * 4096 * 2;
  unsigned short* Wtg = (unsigned short*)ws; ws += (size_t)256 * 8192 * 2;
  unsigned short* Qtg = (unsigned short*)ws; ws += (size_t)256 * 8192 * 2;
  unsigned short* Khg = (unsigned short*)ws; ws += (size_t)256 * 8192 * 2;
  float* bvg          = (float*)ws;          ws += (size_t)256 * 8192 * 4;
  float* esg          = (float*)ws;          ws += 256 * 4;
  float* Wbt          = (float*)ws;          ws += (size_t)32 * HID * 4;     // 256 KB

  cast_bf16<<<dim3(SEQ * HID / 1024), 256, 0, stream>>>(hid, Xb, SEQ * HID);
  transpose_cast2<<<dim3(128, 32), 256, 0, stream>>>(W_qkvz, W1t, W_out, W2t);
  transpose_f32<<<dim3(HID / 32), 256, 0, stream>>>(W_ba, Wbt);
  ba_kernel<<<dim3(SEQ / 4), 256, 0, stream>>>(hid, Wbt, A_log, dt_bias, gbuf, bet);
  // qkvz = X @ W_qkvz  (bf16 output; 64x128 tile, BK=64 -> 768 blocks)
  gemm_bf16<2, 4, 2, true><<<dim3(NQKVZ / 128, SEQ / 64), 256, 0, stream>>>(
      Xb, W1t, qkvz, SEQ, NQKVZ, HID);
  chunk_prep<<<dim3(256), 512, 0, stream>>>(qkvz, conv_w, gbuf, bet,
                                            Tg, Gg, Wtg, Qtg, Khg, bvg, esg);
  scan_rec<<<dim3(128), 256, 0, stream>>>(Tg, Gg, Wtg, Qtg, Khg, bvg, esg, obuf);
  rmsnorm_kernel<<<dim3(SEQ), 256, 0, stream>>>(obuf, qkvz, norm_w, on_bf);
  // out = on @ W_out  (f32 output; 64x64 tile, BK=64 -> 512 blocks)
  gemm_bf16<2, 2, 2, false><<<dim3(HID / 64, SEQ / 64), 256, 0, stream>>>(
      on_bf, W2t, out, SEQ, HID, HID);
}

// Round 16
// 146.429 us; speedup vs baseline: 1.2585x; 1.1690x over previous
//
#include <hip/hip_runtime.h>
#include <hip/hip_bf16.h>
#include <math.h>

// Qwen3-Next GatedDeltaNet, B=1, S=1024, HIDDEN=2048
// H_K=8, H_V=16, DK=DV=128, KDIM=1024, VDIM=2048, CONV_DIM=4096, KS=4
// Chunked delta rule: C=64, 16 chunks. qkvz bf16. ONE merged prep dispatch
// (role-ordered: ba first; zero intra-dispatch producer-consumer edges).

#define SEQ 1024
#define HID 2048
#define NQKVZ 6144

typedef __attribute__((ext_vector_type(8))) short short8;
typedef __attribute__((ext_vector_type(4))) float f32x4;

__device__ __forceinline__ unsigned short f2bf(float f) {
  __hip_bfloat16 h = __float2bfloat16(f);
  return *reinterpret_cast<unsigned short*>(&h);
}
__device__ __forceinline__ float bf2f(unsigned short u) {
  unsigned int x = ((unsigned int)u) << 16;
  return __int_as_float(x);
}

// async global->LDS, 16B per lane (dest = wave-uniform base + lane*16)
typedef __attribute__((address_space(3))) void lds_void;
typedef const __attribute__((address_space(1))) void g_void;
__device__ __forceinline__ void gload16(const void* g, void* l) {
  __builtin_amdgcn_global_load_lds((g_void*)g, (lds_void*)l, 16, 0, 0);
}

// ---------------------------------------------------------------------------
// prep_all: merged {ba-GEMV(direct W_ba), X->bf16, W_qkvz^T, W_out^T}.
// Role order puts ba FIRST so its latency hides under the transposes.
//   [0,256)       ba GEMV, 4 seq rows/block, coalesced float4 W_ba reads
//   [256,2304)    cast X -> bf16 (1024 elems/block)
//   [2304,5376)   W_qkvz transpose-cast 64x64 tiles (96 n x 32 k)
//   [5376,6400)   W_out  transpose-cast 64x64 tiles (32 x 32)
// No role reads anything another role writes.
// ---------------------------------------------------------------------------
__global__ __launch_bounds__(256) void prep_all(
    const float* __restrict__ hid, const float* __restrict__ W_qkvz,
    const float* __restrict__ W_out, const float* __restrict__ W_ba,
    const float* __restrict__ A_log, const float* __restrict__ dt_bias,
    unsigned short* __restrict__ Xb, unsigned short* __restrict__ W1t,
    unsigned short* __restrict__ W2t,
    float* __restrict__ gbuf, float* __restrict__ bet) {
  __shared__ float tile[64][65];
  __shared__ float redba[4][4][8][4];  // [wave][s][cg][c]
  int bx = blockIdx.x;

  if (bx < 256) {  // ---- ba GEMV (direct, coalesced)
    const int cg = threadIdx.x & 7;    // cols cg*4 .. cg*4+3
    const int kg = threadIdx.x >> 3;   // k-slice [kg*64, kg*64+64)
    const int s0 = bx * 4;
    const float* wb = W_ba + (size_t)(kg * 64) * 32 + cg * 4;
    const float* xp = hid + (size_t)s0 * HID + kg * 64;

    float acc[4][4];
#pragma unroll
    for (int s = 0; s < 4; ++s)
#pragma unroll
      for (int cc = 0; cc < 4; ++cc) acc[s][cc] = 0.f;

    for (int kk = 0; kk < 64; kk += 4) {
      const float4 x0 = *(const float4*)&xp[kk];
      const float4 x1 = *(const float4*)&xp[kk + HID];
      const float4 x2 = *(const float4*)&xp[kk + 2 * HID];
      const float4 x3 = *(const float4*)&xp[kk + 3 * HID];
#pragma unroll
      for (int j = 0; j < 4; ++j) {
        const float4 w4 = *(const float4*)&wb[(size_t)(kk + j) * 32];
        const float xs0 = (j == 0) ? x0.x : (j == 1) ? x0.y : (j == 2) ? x0.z : x0.w;
        const float xs1 = (j == 0) ? x1.x : (j == 1) ? x1.y : (j == 2) ? x1.z : x1.w;
        const float xs2 = (j == 0) ? x2.x : (j == 1) ? x2.y : (j == 2) ? x2.z : x2.w;
        const float xs3 = (j == 0) ? x3.x : (j == 1) ? x3.y : (j == 2) ? x3.z : x3.w;
        acc[0][0] = fmaf(xs0, w4.x, acc[0][0]); acc[0][1] = fmaf(xs0, w4.y, acc[0][1]);
        acc[0][2] = fmaf(xs0, w4.z, acc[0][2]); acc[0][3] = fmaf(xs0, w4.w, acc[0][3]);
        acc[1][0] = fmaf(xs1, w4.x, acc[1][0]); acc[1][1] = fmaf(xs1, w4.y, acc[1][1]);
        acc[1][2] = fmaf(xs1, w4.z, acc[1][2]); acc[1][3] = fmaf(xs1, w4.w, acc[1][3]);
        acc[2][0] = fmaf(xs2, w4.x, acc[2][0]); acc[2][1] = fmaf(xs2, w4.y, acc[2][1]);
        acc[2][2] = fmaf(xs2, w4.z, acc[2][2]); acc[2][3] = fmaf(xs2, w4.w, acc[2][3]);
        acc[3][0] = fmaf(xs3, w4.x, acc[3][0]); acc[3][1] = fmaf(xs3, w4.y, acc[3][1]);
        acc[3][2] = fmaf(xs3, w4.z, acc[3][2]); acc[3][3] = fmaf(xs3, w4.w, acc[3][3]);
      }
    }
    // reduce over the 8 kg-values within each wave (lane = kg*8+cg mod 64)
#pragma unroll
    for (int s = 0; s < 4; ++s)
#pragma unroll
      for (int cc = 0; cc < 4; ++cc) {
        float v = acc[s][cc];
        v += __shfl_xor(v, 8);
        v += __shfl_xor(v, 16);
        v += __shfl_xor(v, 32);
        acc[s][cc] = v;
      }
    const int wv = threadIdx.x >> 6;
    if ((threadIdx.x & 63) < 8) {
#pragma unroll
      for (int s = 0; s < 4; ++s)
#pragma unroll
        for (int cc = 0; cc < 4; ++cc) redba[wv][s][cg][cc] = acc[s][cc];
    }
    __syncthreads();
    if (threadIdx.x < 32) {
      const int s = threadIdx.x >> 3, c2 = threadIdx.x & 7;
#pragma unroll
      for (int cc = 0; cc < 4; ++cc) {
        const float a = redba[0][s][c2][cc] + redba[1][s][c2][cc] +
                        redba[2][s][c2][cc] + redba[3][s][c2][cc];
        if (cc < 2) {
          bet[(s0 + s) * 16 + c2 * 2 + cc] = 1.f / (1.f + expf(-a));
        } else {
          const int vh = c2 * 2 + (cc - 2);
          const float x = a + dt_bias[vh];
          const float sp = (x > 20.f) ? x : log1pf(expf(x));
          gbuf[(s0 + s) * 16 + vh] = -expf(A_log[vh]) * sp;
        }
      }
    }
    return;
  }
  bx -= 256;
  if (bx < 2048) {  // ---- X -> bf16
    const int i = (bx * 256 + threadIdx.x) * 4;
    const float4 v = *(const float4*)&hid[i];
    ushort4 o;
    o.x = f2bf(v.x); o.y = f2bf(v.y); o.z = f2bf(v.z); o.w = f2bf(v.w);
    *(ushort4*)&Xb[i] = o;
    return;
  }
  bx -= 2048;
  {  // ---- transpose-cast 64x64 (W_qkvz then W_out)
    const float* W;
    unsigned short* Wt;
    int N, n0, k0;
    if (bx < 3072) { W = W_qkvz; Wt = W1t; N = NQKVZ; n0 = (bx % 96) * 64; k0 = (bx / 96) * 64; }
    else { bx -= 3072; W = W_out; Wt = W2t; N = HID; n0 = (bx & 31) * 64; k0 = (bx >> 5) * 64; }
    const int tc = (threadIdx.x & 15) * 4;
    const int tr = threadIdx.x >> 4;
#pragma unroll
    for (int rr = 0; rr < 64; rr += 16) {
      const float4 v = *(const float4*)&W[(size_t)(k0 + tr + rr) * N + n0 + tc];
      *(float4*)&tile[tr + rr][tc] = v;
    }
    __syncthreads();
#pragma unroll
    for (int rr = 0; rr < 64; rr += 16) {
      const int r = tr + rr;
      ushort4 o;
      o.x = f2bf(tile[tc + 0][r]);
      o.y = f2bf(tile[tc + 1][r]);
      o.z = f2bf(tile[tc + 2][r]);
      o.w = f2bf(tile[tc + 3][r]);
      *(ushort4*)&Wt[(size_t)(n0 + r) * HID + k0 + tc] = o;
    }
  }
}

// ---------------------------------------------------------------------------
// bf16 MFMA GEMM: C = A @ Bt^T. OUTBF selects bf16 or f32 C.
// Block tile (32*MF)x(32*NF), BK=32*KF, 4 waves (2x2).
// ---------------------------------------------------------------------------
#define SWZ(row) ((KF == 1) ? (((row) >> 1) & 3) : ((row) & 7))

template <int MF, int NF, int KF, bool OUTBF>
__global__ __launch_bounds__(256) void gemm_bf16(const unsigned short* __restrict__ A,
                                                 const unsigned short* __restrict__ Bt,
                                                 void* __restrict__ Cv,
                                                 int M, int N, int K) {
  constexpr int BM = 32 * MF, BN = 32 * NF, BK = 32 * KF;
  constexpr int RB  = BK * 2;
  constexpr int APW = (BM * KF / 16) / 4;
  constexpr int BPW = (BN * KF / 16) / 4;
  constexpr int RPG = 16 / KF;
  __shared__ unsigned short As[2][BM * BK];
  __shared__ unsigned short Bs[2][BN * BK];

  const int tid  = threadIdx.x;
  const int lane = tid & 63;
  const int w    = tid >> 6;
  const int wm   = w >> 1, wn = w & 1;
  const int row0 = blockIdx.y * BM, col0 = blockIdx.x * BN;

  const int lrow  = (KF == 1) ? (lane >> 2) : (lane >> 3);
  const int lslot = lane & (4 * KF - 1);
  const int arow  = lane & 15;

  f32x4 acc[MF][NF];
#pragma unroll
  for (int m = 0; m < MF; ++m)
#pragma unroll
    for (int n = 0; n < NF; ++n) acc[m][n] = (f32x4){0.f, 0.f, 0.f, 0.f};

  auto stage = [&](int bi, int kt) {
    const int ko = kt * BK;
#pragma unroll
    for (int u = 0; u < APW; ++u) {
      const int gu = w * APW + u;
      const int row = gu * RPG + lrow;
      const int sg = lslot ^ SWZ(row);
      gload16(A + (size_t)(row0 + row) * K + ko + sg * 8,
              (char*)As[bi] + gu * 1024 + lane * 16);
    }
#pragma unroll
    for (int u = 0; u < BPW; ++u) {
      const int gu = w * BPW + u;
      const int row = gu * RPG + lrow;
      const int sg = lslot ^ SWZ(row);
      gload16(Bt + (size_t)(col0 + row) * K + ko + sg * 8,
              (char*)Bs[bi] + gu * 1024 + lane * 16);
    }
  };

  stage(0, 0);
  __syncthreads();

  int cur = 0;
  const int nk = K / BK;
  for (int kt = 0; kt < nk; ++kt) {
    if (kt + 1 < nk) stage(cur ^ 1, kt + 1);

    const char* asb = (const char*)As[cur];
    const char* bsb = (const char*)Bs[cur];
    short8 af[MF][KF], bf[NF][KF];
#pragma unroll
    for (int m = 0; m < MF; ++m)
#pragma unroll
      for (int kk = 0; kk < KF; ++kk) {
        const int row = wm * (16 * MF) + m * 16 + arow;
        const int slot = kk * 4 + (lane >> 4);
        af[m][kk] = *(const short8*)(asb + row * RB + ((slot ^ SWZ(row)) * 16));
      }
#pragma unroll
    for (int n = 0; n < NF; ++n)
#pragma unroll
      for (int kk = 0; kk < KF; ++kk) {
        const int row = wn * (16 * NF) + n * 16 + arow;
        const int slot = kk * 4 + (lane >> 4);
        bf[n][kk] = *(const short8*)(bsb + row * RB + ((slot ^ SWZ(row)) * 16));
      }
#pragma unroll
    for (int m = 0; m < MF; ++m)
#pragma unroll
      for (int n = 0; n < NF; ++n)
#pragma unroll
        for (int kk = 0; kk < KF; ++kk)
          acc[m][n] = __builtin_amdgcn_mfma_f32_16x16x32_bf16(af[m][kk], bf[n][kk],
                                                              acc[m][n], 0, 0, 0);

    __syncthreads();
    cur ^= 1;
  }

#pragma unroll
  for (int m = 0; m < MF; ++m)
#pragma unroll
    for (int n = 0; n < NF; ++n) {
      const int r0 = row0 + wm * (16 * MF) + m * 16 + (lane >> 4) * 4;
      const int c  = col0 + wn * (16 * NF) + n * 16 + (lane & 15);
#pragma unroll
      for (int r = 0; r < 4; ++r) {
        if (OUTBF)
          ((unsigned short*)Cv)[(size_t)(r0 + r) * N + c] = f2bf(acc[m][n][r]);
        else
          ((float*)Cv)[(size_t)(r0 + r) * N + c] = acc[m][n][r];
      }
    }
}

// ---------------------------------------------------------------------------
// chunk_prep v7: qkvz bf16 input. ONE staging burst for q+k+v, 3 barriers.
// Waves 0-3 KK^T, 4-7 QK^T; wave 0 reg-solve || 7-wave epilogue.
// ---------------------------------------------------------------------------
#define NT 512
__global__ __launch_bounds__(NT) void chunk_prep(
    const unsigned short* __restrict__ qkvz, const float* __restrict__ conv_w,
    const float* __restrict__ gbuf, const float* __restrict__ bet,
    unsigned short* __restrict__ Tg, unsigned short* __restrict__ Gg,
    unsigned short* __restrict__ Wtg, unsigned short* __restrict__ Qtg,
    unsigned short* __restrict__ Khg, float* __restrict__ bvg,
    float* __restrict__ esg) {
  const int h  = blockIdx.x >> 4;
  const int c  = blockIdx.x & 15;
  const int hk = h >> 1;
  const int tid = threadIdx.x;
  const int lane = tid & 63;
  const int w    = tid >> 6;
  const int lr   = lane & 15;
  const int lk   = lane >> 4;

  __shared__ unsigned short rawq[67 * 132];
  __shared__ unsigned short rawk[67 * 132];
  __shared__ unsigned short rawv[67 * 132];
  __shared__ unsigned short Kb[64 * 128];
  __shared__ unsigned short Qb[64 * 128];
  __shared__ unsigned short Bm[64][64];
  __shared__ float cg[64];
  __shared__ float btl[64];

  const int s0 = c * 64;
  const int qcol0 = hk * 768;
  const int kcol0 = hk * 768 + 128;
  const int vcol0 = hk * 768 + 256 + (h & 1) * 128;

  ushort4 rq[5], rk[5], rv[5];
#pragma unroll
  for (int ii = 0; ii < 5; ++ii) {
    const int idx = tid + NT * ii;
    if (idx < 67 * 32) {
      const int r = idx >> 5, cq = (idx & 31) * 4;
      const int sr = s0 - 3 + r;
      if (sr >= 0) {
        rq[ii] = *(const ushort4*)&qkvz[(size_t)sr * NQKVZ + qcol0 + cq];
        rk[ii] = *(const ushort4*)&qkvz[(size_t)sr * NQKVZ + kcol0 + cq];
        rv[ii] = *(const ushort4*)&qkvz[(size_t)sr * NQKVZ + vcol0 + cq];
      } else {
        rq[ii] = (ushort4){0, 0, 0, 0};
        rk[ii] = (ushort4){0, 0, 0, 0};
        rv[ii] = (ushort4){0, 0, 0, 0};
      }
    }
  }
  if (tid < 64) {
    float g = gbuf[(s0 + tid) * 16 + h];
#pragma unroll
    for (int d = 1; d < 64; d <<= 1) {
      const float o = __shfl_up(g, d);
      if (tid >= d) g += o;
    }
    cg[tid] = g;
    btl[tid] = bet[(s0 + tid) * 16 + h];
  }
#pragma unroll
  for (int ii = 0; ii < 5; ++ii) {
    const int idx = tid + NT * ii;
    if (idx < 67 * 32) {
      const int r = idx >> 5, cq = (idx & 31) * 4;
      *(ushort4*)&rawq[r * 132 + cq] = rq[ii];
      *(ushort4*)&rawk[r * 132 + cq] = rk[ii];
      *(ushort4*)&rawv[r * 132 + cq] = rv[ii];
    }
  }
  __syncthreads();

#define CONV_TO(dst, rawsrc, wbase, isq)                                      \
  for (int n = 0; n < 4; ++n) {                                               \
    const int idx = tid + NT * n;                                             \
    const int row = idx >> 5;                                                 \
    const int col = (idx & 31) * 4;                                           \
    float wgt[4][4];                                                          \
    _Pragma("unroll")                                                         \
    for (int x = 0; x < 4; ++x) {                                             \
      const float4 a = *(const float4*)&conv_w[((wbase) + hk * 128 + col + x) * 4]; \
      wgt[x][0] = a.x; wgt[x][1] = a.y; wgt[x][2] = a.z; wgt[x][3] = a.w;     \
    }                                                                         \
    float4 ac = {0.f, 0.f, 0.f, 0.f};                                         \
    _Pragma("unroll")                                                         \
    for (int j = 0; j < 4; ++j) {                                             \
      const ushort4 xr4 = *(const ushort4*)&rawsrc[(row + j) * 132 + col];    \
      ac.x = fmaf(wgt[0][j], bf2f(xr4.x), ac.x);                              \
      ac.y = fmaf(wgt[1][j], bf2f(xr4.y), ac.y);                              \
      ac.z = fmaf(wgt[2][j], bf2f(xr4.z), ac.z);                              \
      ac.w = fmaf(wgt[3][j], bf2f(xr4.w), ac.w);                              \
    }                                                                         \
    float4 y;                                                                 \
    y.x = ac.x / (1.f + __expf(-ac.x)); y.y = ac.y / (1.f + __expf(-ac.y));   \
    y.z = ac.z / (1.f + __expf(-ac.z)); y.w = ac.w / (1.f + __expf(-ac.w));   \
    float ss = y.x * y.x + y.y * y.y + y.z * y.z + y.w * y.w;                 \
    _Pragma("unroll")                                                         \
    for (int m = 1; m <= 16; m <<= 1) ss += __shfl_xor(ss, m);                \
    float sc = rsqrtf(ss + 1e-6f);                                            \
    if (isq) sc *= 0.08838834764831845f;                                      \
    const int boff = row * 256 + ((col * 2) ^ ((row & 7) << 4));              \
    ushort4 o = {f2bf(y.x * sc), f2bf(y.y * sc), f2bf(y.z * sc), f2bf(y.w * sc)}; \
    *(ushort4*)((char*)(dst) + boff) = o;                                     \
  }

  CONV_TO(Qb, rawq, 0, true);
  CONV_TO(Kb, rawk, 1024, false);
  __syncthreads();

  const bool isK = (w < 4);
  const int w4 = w & 3;
  f32x4 dacc[4];
#pragma unroll
  for (int ct = 0; ct < 4; ++ct) dacc[ct] = (f32x4){0.f, 0.f, 0.f, 0.f};
  {
    const int rowA = 16 * w4 + lr;
    const int swA  = (rowA & 7) << 4;
    const char* Ab = isK ? (const char*)Kb : (const char*)Qb;
#pragma unroll
    for (int ks = 0; ks < 4; ++ks) {
      const int kb = ks * 64 + lk * 16;
      const short8 a = *(const short8*)(Ab + rowA * 256 + (kb ^ swA));
#pragma unroll
      for (int ct = 0; ct < 4; ++ct) {
        const int rowB = ct * 16 + lr;
        const short8 bK = *(const short8*)((char*)Kb + rowB * 256 + (kb ^ ((rowB & 7) << 4)));
        dacc[ct] = __builtin_amdgcn_mfma_f32_16x16x32_bf16(a, bK, dacc[ct], 0, 0, 0);
      }
    }
  }
#pragma unroll
  for (int ct = 0; ct < 4; ++ct) {
#pragma unroll
    for (int r = 0; r < 4; ++r) {
      const int i = 16 * w4 + lk * 4 + r;
      const int j = ct * 16 + lr;
      const float e = __expf(cg[i] - cg[j]);
      if (isK) Bm[i][j] = f2bf((j < i) ? btl[i] * e * dacc[ct][r] : 0.f);
      else     Gg[(size_t)blockIdx.x * 4096 + i * 64 + j] =
                   f2bf((j <= i) ? e * dacc[ct][r] : 0.f);
    }
  }
  __syncthreads();

  const float cglast = cg[63];
  if (w == 0) {
    const int l = lane;
    float Tc[64];
#pragma unroll
    for (int i = 0; i < 64; ++i) {
      float v = (i == l) ? 1.f : 0.f;
#pragma unroll
      for (int j = 0; j < i; ++j) v -= bf2f(Bm[i][j]) * Tc[j];
      Tc[i] = v;
    }
#pragma unroll
    for (int i = 0; i < 64; ++i)
      Tg[(size_t)blockIdx.x * 4096 + i * 64 + l] = f2bf(Tc[i]);
    if (lane == 0) esg[blockIdx.x] = __expf(cglast);
  } else {
    const int t2 = tid - 64;
    for (int idx = t2; idx < 2048; idx += 448) {
      const int i = idx >> 5;
      const int dk = (idx & 31) * 4;
      const int boff = i * 256 + ((dk * 2) ^ ((i & 7) << 4));
      const ushort4 kq = *(const ushort4*)((char*)Kb + boff);
      const ushort4 qq = *(const ushort4*)((char*)Qb + boff);
      const float ei = __expf(cg[i]);
      const float wi = btl[i] * ei;
      ushort4 wo = {f2bf(wi * bf2f(kq.x)), f2bf(wi * bf2f(kq.y)),
                    f2bf(wi * bf2f(kq.z)), f2bf(wi * bf2f(kq.w))};
      ushort4 qo = {f2bf(ei * bf2f(qq.x)), f2bf(ei * bf2f(qq.y)),
                    f2bf(ei * bf2f(qq.z)), f2bf(ei * bf2f(qq.w))};
      *(ushort4*)&Wtg[(size_t)blockIdx.x * 8192 + i * 128 + dk] = wo;
      *(ushort4*)&Qtg[(size_t)blockIdx.x * 8192 + i * 128 + dk] = qo;

      float wv[4][4];
#pragma unroll
      for (int x = 0; x < 4; ++x) {
        const float4 a = *(const float4*)&conv_w[(2048 + h * 128 + dk + x) * 4];
        wv[x][0] = a.x; wv[x][1] = a.y; wv[x][2] = a.z; wv[x][3] = a.w;
      }
      float4 va = {0.f, 0.f, 0.f, 0.f};
#pragma unroll
      for (int j = 0; j < 4; ++j) {
        const ushort4 xv4 = *(const ushort4*)&rawv[(i + j) * 132 + dk];
        va.x = fmaf(wv[0][j], bf2f(xv4.x), va.x);
        va.y = fmaf(wv[1][j], bf2f(xv4.y), va.y);
        va.z = fmaf(wv[2][j], bf2f(xv4.z), va.z);
        va.w = fmaf(wv[3][j], bf2f(xv4.w), va.w);
      }
      float4 bv4;
      bv4.x = btl[i] * va.x / (1.f + __expf(-va.x));
      bv4.y = btl[i] * va.y / (1.f + __expf(-va.y));
      bv4.z = btl[i] * va.z / (1.f + __expf(-va.z));
      bv4.w = btl[i] * va.w / (1.f + __expf(-va.w));
      *(float4*)&bvg[(size_t)blockIdx.x * 8192 + i * 128 + dk] = bv4;
    }
    for (int lin = t2; lin < 8192; lin += 448) {
      const int dk = lin >> 6, i = lin & 63;
      const unsigned short kraw =
          *(const unsigned short*)((char*)Kb + i * 256 + ((dk * 2) ^ ((i & 7) << 4)));
      Khg[(size_t)blockIdx.x * 8192 + lin] = f2bf(__expf(cglast - cg[i]) * bf2f(kraw));
    }
  }
#undef CONV_TO
}
#undef NT

// ---------------------------------------------------------------------------
// scan_rec: serial over 16 chunks, (h, dv-block) parallel,
// h = bid&15 -> same-head blocks share one XCD's L2; reg-prefetch 2 sets.
// ---------------------------------------------------------------------------
struct SFrags {
  short8 wf[4];
  short8 tf[2];
  short8 qf[4];
  short8 gf[2];
  short8 kh[2][2];
  float  bv[4];
  float  es;
};

__device__ __forceinline__ void sload(SFrags& F,
    const unsigned short* __restrict__ Tg, const unsigned short* __restrict__ Gg,
    const unsigned short* __restrict__ Wtg, const unsigned short* __restrict__ Qtg,
    const unsigned short* __restrict__ Khg, const float* __restrict__ bvg,
    const float* __restrict__ esg,
    size_t base, int w, int lr, int lk, int dv0) {
  const unsigned short* T_  = Tg  + base * 4096;
  const unsigned short* G_  = Gg  + base * 4096;
  const unsigned short* W_  = Wtg + base * 8192;
  const unsigned short* Q_  = Qtg + base * 8192;
  const unsigned short* Kh_ = Khg + base * 8192;
  const float* bv_ = bvg + base * 8192;
#pragma unroll
  for (int ks = 0; ks < 4; ++ks) {
    F.wf[ks] = *(const short8*)(W_ + (16 * w + lr) * 128 + ks * 32 + lk * 8);
    F.qf[ks] = *(const short8*)(Q_ + (16 * w + lr) * 128 + ks * 32 + lk * 8);
  }
#pragma unroll
  for (int ks = 0; ks < 2; ++ks) {
    F.tf[ks]    = *(const short8*)(T_ + (16 * w + lr) * 64 + ks * 32 + lk * 8);
    F.gf[ks]    = *(const short8*)(G_ + (16 * w + lr) * 64 + ks * 32 + lk * 8);
    F.kh[0][ks] = *(const short8*)(Kh_ + (32 * w + lr) * 64 + ks * 32 + lk * 8);
    F.kh[1][ks] = *(const short8*)(Kh_ + (32 * w + 16 + lr) * 64 + ks * 32 + lk * 8);
  }
#pragma unroll
  for (int r = 0; r < 4; ++r)
    F.bv[r] = bv_[(16 * w + lk * 4 + r) * 128 + dv0 + lr];
  F.es = esg[base];
}

__global__ __launch_bounds__(256) void scan_rec(
    const unsigned short* __restrict__ Tg, const unsigned short* __restrict__ Gg,
    const unsigned short* __restrict__ Wtg, const unsigned short* __restrict__ Qtg,
    const unsigned short* __restrict__ Khg, const float* __restrict__ bvg,
    const float* __restrict__ esg, float* __restrict__ obuf) {
  const int h   = blockIdx.x & 15;
  const int dvb = blockIdx.x >> 4;
  const int dv0 = dvb * 16;
  const int tid = threadIdx.x;
  const int lane = tid & 63;
  const int w   = tid >> 6;
  const int lr  = lane & 15;
  const int lk  = lane >> 4;

  __shared__ unsigned short Sb[16][136];
  __shared__ unsigned short Ub[16][72];
  __shared__ unsigned short Db[16][72];

  for (int n = tid; n < 16 * 136 / 2; n += 256) ((unsigned int*)Sb)[n] = 0u;

  f32x4 sacc0 = {0.f, 0.f, 0.f, 0.f};
  f32x4 sacc1 = {0.f, 0.f, 0.f, 0.f};

  SFrags fA, fB;
  sload(fA, Tg, Gg, Wtg, Qtg, Khg, bvg, esg, (size_t)h * 16, w, lr, lk, dv0);
  __syncthreads();

#define SCAN_CHUNK(F, c)                                                      \
  {                                                                           \
    short8 sb[4];                                                             \
    _Pragma("unroll")                                                         \
    for (int ks = 0; ks < 4; ++ks)                                            \
      sb[ks] = *(const short8*)(&Sb[lr][ks * 32 + lk * 8]);                   \
    f32x4 au = {0.f, 0.f, 0.f, 0.f};                                          \
    _Pragma("unroll")                                                         \
    for (int ks = 0; ks < 4; ++ks)                                            \
      au = __builtin_amdgcn_mfma_f32_16x16x32_bf16(F.wf[ks], sb[ks], au, 0, 0, 0); \
    {                                                                         \
      ushort4 pk;                                                             \
      _Pragma("unroll")                                                       \
      for (int r = 0; r < 4; ++r)                                             \
        ((unsigned short*)&pk)[r] = f2bf(F.bv[r] - au[r]);                    \
      *(ushort4*)&Ub[lr][16 * w + lk * 4] = pk;                               \
    }                                                                         \
    __syncthreads();                                                          \
    f32x4 ad = {0.f, 0.f, 0.f, 0.f};                                          \
    _Pragma("unroll")                                                         \
    for (int ks = 0; ks < 2; ++ks) {                                          \
      const short8 ub = *(const short8*)(&Ub[lr][ks * 32 + lk * 8]);          \
      ad = __builtin_amdgcn_mfma_f32_16x16x32_bf16(F.tf[ks], ub, ad, 0, 0, 0); \
    }                                                                         \
    {                                                                         \
      ushort4 pk;                                                             \
      _Pragma("unroll")                                                       \
      for (int r = 0; r < 4; ++r) ((unsigned short*)&pk)[r] = f2bf(ad[r]);    \
      *(ushort4*)&Db[lr][16 * w + lk * 4] = pk;                               \
    }                                                                         \
    __syncthreads();                                                          \
    short8 dbf[2];                                                            \
    _Pragma("unroll")                                                         \
    for (int ks = 0; ks < 2; ++ks)                                            \
      dbf[ks] = *(const short8*)(&Db[lr][ks * 32 + lk * 8]);                  \
    f32x4 ao = {0.f, 0.f, 0.f, 0.f};                                          \
    _Pragma("unroll")                                                         \
    for (int ks = 0; ks < 4; ++ks)                                            \
      ao = __builtin_amdgcn_mfma_f32_16x16x32_bf16(F.qf[ks], sb[ks], ao, 0, 0, 0); \
    _Pragma("unroll")                                                         \
    for (int ks = 0; ks < 2; ++ks)                                            \
      ao = __builtin_amdgcn_mfma_f32_16x16x32_bf16(F.gf[ks], dbf[ks], ao, 0, 0, 0); \
    _Pragma("unroll")                                                         \
    for (int r = 0; r < 4; ++r) {                                             \
      const int i = 16 * w + lk * 4 + r;                                      \
      obuf[((size_t)((c) * 64 + i) * 16 + h) * 128 + dv0 + lr] = ao[r];       \
    }                                                                         \
    sacc0 *= F.es;                                                            \
    sacc1 *= F.es;                                                            \
    _Pragma("unroll")                                                         \
    for (int ks = 0; ks < 2; ++ks) {                                          \
      sacc0 = __builtin_amdgcn_mfma_f32_16x16x32_bf16(F.kh[0][ks], dbf[ks], sacc0, 0, 0, 0); \
      sacc1 = __builtin_amdgcn_mfma_f32_16x16x32_bf16(F.kh[1][ks], dbf[ks], sacc1, 0, 0, 0); \
    }                                                                         \
    {                                                                         \
      ushort4 p0, p1;                                                         \
      _Pragma("unroll")                                                       \
      for (int r = 0; r < 4; ++r) {                                           \
        ((unsigned short*)&p0)[r] = f2bf(sacc0[r]);                           \
        ((unsigned short*)&p1)[r] = f2bf(sacc1[r]);                           \
      }                                                                       \
      *(ushort4*)&Sb[lr][32 * w + lk * 4] = p0;                               \
      *(ushort4*)&Sb[lr][32 * w + 16 + lk * 4] = p1;                          \
    }                                                                         \
    __syncthreads();                                                          \
  }

  for (int c = 0; c < 16; c += 2) {
    const int c1 = (c + 1 < 15) ? c + 1 : 15;
    const int c2 = (c + 2 < 15) ? c + 2 : 15;
    sload(fB, Tg, Gg, Wtg, Qtg, Khg, bvg, esg, (size_t)h * 16 + c1, w, lr, lk, dv0);
    SCAN_CHUNK(fA, c);
    sload(fA, Tg, Gg, Wtg, Qtg, Khg, bvg, esg, (size_t)h * 16 + c2, w, lr, lk, dv0);
    SCAN_CHUNK(fB, c + 1);
  }
#undef SCAN_CHUNK
}

// ---------------------------------------------------------------------------
// gated RMSNorm -> bf16 (z read from bf16 qkvz)
// ---------------------------------------------------------------------------
__global__ __launch_bounds__(256) void rmsnorm_kernel(const float* __restrict__ obuf,
                                                      const unsigned short* __restrict__ qkvz,
                                                      const float* __restrict__ nw,
                                                      unsigned short* __restrict__ on) {
  const int s    = blockIdx.x;
  const int half = threadIdx.x >> 7;
  const int d    = threadIdx.x & 127;
  __shared__ float red[4];

  for (int it = 0; it < 8; ++it) {
    const int vh = it * 2 + half;
    const float x = obuf[((size_t)s * 16 + vh) * 128 + d];
    float ss = x * x;
#pragma unroll
    for (int m = 1; m < 64; m <<= 1) ss += __shfl_xor(ss, m);
    if ((threadIdx.x & 63) == 0) red[threadIdx.x >> 6] = ss;
    __syncthreads();
    const float tot = red[half * 2] + red[half * 2 + 1];

    const float z = bf2f(qkvz[(size_t)s * NQKVZ + (vh >> 1) * 768 + 512 + (vh & 1) * 128 + d]);
    const float y = x * rsqrtf(tot * (1.f / 128.f) + 1e-6f) * nw[d] *
                    (z / (1.f + expf(-z)));
    on[(size_t)s * 2048 + vh * 128 + d] = f2bf(y);
    __syncthreads();
  }
}

// ---------------------------------------------------------------------------
extern "C" void kernel_launch(void* const* d_in, const int* in_sizes, int n_in,
                              void* d_out, int out_size, void* d_ws, size_t ws_size,
                              hipStream_t stream) {
  const float* hid     = (const float*)d_in[0];
  const float* W_qkvz  = (const float*)d_in[1];
  const float* W_ba    = (const float*)d_in[2];
  const float* conv_w  = (const float*)d_in[3];
  const float* dt_bias = (const float*)d_in[4];
  const float* A_log   = (const float*)d_in[5];
  const float* norm_w  = (const float*)d_in[6];
  const float* W_out   = (const float*)d_in[7];
  float* out = (float*)d_out;

  char* ws = (char*)d_ws;
  unsigned short* qkvz = (unsigned short*)ws; ws += (size_t)SEQ * NQKVZ * 2; // 12 MB
  char* region2 = ws;                       ws += (size_t)HID * NQKVZ * 2;   // 24 MB
  unsigned short* W1t = (unsigned short*)region2;
  float* obuf = (float*)(region2 + 16777216);
  unsigned short* Xb = (unsigned short*)ws; ws += (size_t)SEQ * HID * 2;     // 4 MB
  unsigned short* on_bf = Xb;
  unsigned short* W2t = (unsigned short*)ws; ws += (size_t)HID * HID * 2;    // 8 MB
  float* gbuf = (float*)ws;                  ws += (size_t)SEQ * 16 * 4;
  float* bet  = (float*)ws;                  ws += (size_t)SEQ * 16 * 4;
  unsigned short* Tg  = (unsigned short*)ws; ws += (size_t)256 * 4096 * 2;
  unsigned short* Gg  = (unsigned short*)ws; ws += (size_t)256 * 4096 * 2;
  unsigned short* Wtg = (unsigned short*)ws; ws += (size_t)256 * 8192 * 2;
  unsigned short* Qtg = (unsigned short*)ws; ws += (size_t)256 * 8192 * 2;
  unsigned short* Khg = (unsigned short*)ws; ws += (size_t)256 * 8192 * 2;
  float* bvg          = (float*)ws;          ws += (size_t)256 * 8192 * 4;
  float* esg          = (float*)ws;          ws += 256 * 4;

  // ONE merged prep dispatch (ba role first; no intra-dispatch deps)
  prep_all<<<dim3(6400), 256, 0, stream>>>(hid, W_qkvz, W_out, W_ba,
                                           A_log, dt_bias,
                                           Xb, W1t, W2t, gbuf, bet);
  // qkvz = X @ W_qkvz  (bf16 output; 64x128 tile, BK=64 -> 768 blocks)
  gemm_bf16<2, 4, 2, true><<<dim3(NQKVZ / 128, SEQ / 64), 256, 0, stream>>>(
      Xb, W1t, qkvz, SEQ, NQKVZ, HID);
  chunk_prep<<<dim3(256), 512, 0, stream>>>(qkvz, conv_w, gbuf, bet,
                                            Tg, Gg, Wtg, Qtg, Khg, bvg, esg);
  scan_rec<<<dim3(128), 256, 0, stream>>>(Tg, Gg, Wtg, Qtg, Khg, bvg, esg, obuf);
  rmsnorm_kernel<<<dim3(SEQ), 256, 0, stream>>>(obuf, qkvz, norm_w, on_bf);
  // out = on @ W_out  (f32 output; 64x64 tile, BK=64 -> 512 blocks)
  gemm_bf16<2, 2, 2, false><<<dim3(HID / 64, SEQ / 64), 256, 0, stream>>>(
      on_bf, W2t, out, SEQ, HID, HID);
}